// Round 6
// baseline (408.522 us; speedup 1.0000x reference)
//
#include <hip/hip_runtime.h>

#define CH 128
#define DS 24
#define HW (DS*DS)      // 576
#define VS (DS*DS*DS)   // 13824

typedef _Float16 f16x8 __attribute__((ext_vector_type(8)));
typedef _Float16 half2v __attribute__((ext_vector_type(2)));
typedef __attribute__((ext_vector_type(4))) float f32x4;
typedef _Float16 h4 __attribute__((ext_vector_type(4)));

__device__ __forceinline__ half2v u2h(unsigned u) {
  union { unsigned u; half2v h; } v; v.u = u; return v.h;
}
__device__ __forceinline__ unsigned h2u(half2v h) {
  union { unsigned u; half2v h; } v; v.h = h; return v.u;
}

// ---------------------------------------------------------------------------
// K0: weight prep, coalesced via LDS transpose.
//  blocks [0,96):    WTh[k][96 o][128 c] fp16 (o>=81 zero)
//  blocks [96,224):  WDh[k][128 o][128 c] fp16
//  block  224:       W1h[o][128 c] fp16 (straight cast, no transpose)
// ---------------------------------------------------------------------------
__global__ __launch_bounds__(256) void prep_weights(
    const float* __restrict__ w_off, const float* __restrict__ w_def,
    const float* __restrict__ w1,
    _Float16* __restrict__ WTh, _Float16* __restrict__ WDh,
    _Float16* __restrict__ W1h) {
  __shared__ float sbuf[3456];
  const int b = blockIdx.x, t = threadIdx.x;
  if (b < 96) {
    const int o = b;
    if (o < 81) {
      for (int s = t; s < 3456; s += 256) sbuf[s] = w_off[o*3456 + s];
      __syncthreads();
      for (int s = t; s < 3456; s += 256) {
        int k = s >> 7, c = s & 127;
        WTh[(k*96 + o)*128 + c] = (_Float16)sbuf[c*27 + k];
      }
    } else {
      for (int s = t; s < 3456; s += 256) {
        int k = s >> 7, c = s & 127;
        WTh[(k*96 + o)*128 + c] = (_Float16)0.f;
      }
    }
  } else if (b < 224) {
    const int o = b - 96;
    for (int s = t; s < 3456; s += 256) sbuf[s] = w_def[o*3456 + s];
    __syncthreads();
    for (int s = t; s < 3456; s += 256) {
      int k = s >> 7, c = s & 127;
      WDh[(k*128 + o)*128 + c] = (_Float16)sbuf[c*27 + k];
    }
  } else {
    for (int s = t; s < 16384; s += 256) W1h[s] = (_Float16)w1[s];
  }
}

// ---------------------------------------------------------------------------
// K1: depthwise 5x5x5, pad=2.  Block per (channel, z-quarter of 6).
// ---------------------------------------------------------------------------
__global__ __launch_bounds__(256) void dw5_kernel(
    const float* __restrict__ x, const float* __restrict__ w0,
    const float* __restrict__ b0, float* __restrict__ A1) {
  const int c  = blockIdx.x >> 2;
  const int zb = (blockIdx.x & 3) * 6;
  __shared__ __align__(16) float sin_[10*24*36];
  __shared__ float sw[128];
  const int t = threadIdx.x;
  if (t < 125) sw[t] = w0[c*125 + t];
  const float* xc = x + c*VS;
  for (int i = t; i < 10*24*36; i += 256) {
    int px = i % 36;
    int y  = (i / 36) % 24;
    int pz = i / (36*24);
    int xx = px - 2;
    int zz = zb - 2 + pz;
    float v = 0.f;
    if ((unsigned)xx < 24u && (unsigned)zz < 24u) v = xc[zz*HW + y*DS + xx];
    sin_[i] = v;
  }
  __syncthreads();
  const float bias = b0[c];
  for (int g = t; g < 6*24*6; g += 256) {
    int xg = g % 6;
    int y  = (g / 6) % 24;
    int zl = g / 144;
    int x0 = xg * 4;
    float a0=0.f, a1=0.f, a2=0.f, a3=0.f;
    for (int kz = 0; kz < 5; ++kz) {
      int pz = zl + kz;
      for (int ky = 0; ky < 5; ++ky) {
        int yy = y + ky - 2;
        if ((unsigned)yy >= 24u) continue;
        const float* row = &sin_[(pz*24 + yy)*36 + x0];
        float4 r0 = *(const float4*)(row);
        float4 r1 = *(const float4*)(row+4);
        float4 r2 = *(const float4*)(row+8);
        float f[12] = {r0.x,r0.y,r0.z,r0.w, r1.x,r1.y,r1.z,r1.w,
                       r2.x,r2.y,r2.z,r2.w};
        const float* wr = &sw[(kz*5+ky)*5];
        #pragma unroll
        for (int kx = 0; kx < 5; ++kx) {
          float w = wr[kx];
          a0 = fmaf(w, f[kx],   a0);
          a1 = fmaf(w, f[kx+1], a1);
          a2 = fmaf(w, f[kx+2], a2);
          a3 = fmaf(w, f[kx+3], a3);
        }
      }
    }
    int z = zb + zl;
    int v = (z*DS + y)*DS + x0;
    *(float4*)&A1[c*VS + v] = make_float4(a0+bias, a1+bias, a2+bias, a3+bias);
  }
}

// ---------------------------------------------------------------------------
// K2: depthwise 5x5x5 dil=3 pad=6 + fused transpose to A2th[v][128 c] fp16.
// ---------------------------------------------------------------------------
__global__ __launch_bounds__(256) void dwdil_kernel(
    const float* __restrict__ A1, const float* __restrict__ wgt,
    const float* __restrict__ bs, _Float16* __restrict__ A2th) {
  const int c  = blockIdx.x >> 2;
  const int zb = (blockIdx.x & 3) * 6;
  __shared__ __align__(16) float sin_[18*24*36];
  __shared__ float sw[128];
  const int t = threadIdx.x;
  if (t < 125) sw[t] = wgt[c*125 + t];
  const float* xc = A1 + c*VS;
  for (int i = t; i < 18*24*36; i += 256) {
    int px = i % 36;
    int y  = (i / 36) % 24;
    int pz = i / (36*24);
    int xx = px - 6;
    int zz = zb - 6 + pz;
    float v = 0.f;
    if ((unsigned)xx < 24u && (unsigned)zz < 24u) v = xc[zz*HW + y*DS + xx];
    sin_[i] = v;
  }
  __syncthreads();
  const float bias = bs[c];
  for (int g = t; g < 6*24*6; g += 256) {
    int xg = g % 6;
    int y  = (g / 6) % 24;
    int zl = g / 144;   // 0..5
    int x0 = xg * 4;
    float a0=0.f, a1=0.f, a2=0.f, a3=0.f;
    for (int kz = 0; kz < 5; ++kz) {
      int pz = zl + 3*kz;
      for (int ky = 0; ky < 5; ++ky) {
        int yy = y + 3*ky - 6;
        if ((unsigned)yy >= 24u) continue;
        const float* row = &sin_[(pz*24 + yy)*36 + x0];
        float4 r0 = *(const float4*)(row);
        float4 r1 = *(const float4*)(row+4);
        float4 r2 = *(const float4*)(row+8);
        float4 r3 = *(const float4*)(row+12);
        float f[16] = {r0.x,r0.y,r0.z,r0.w, r1.x,r1.y,r1.z,r1.w,
                       r2.x,r2.y,r2.z,r2.w, r3.x,r3.y,r3.z,r3.w};
        const float* wr = &sw[(kz*5+ky)*5];
        #pragma unroll
        for (int kx = 0; kx < 5; ++kx) {
          float w = wr[kx];
          a0 = fmaf(w, f[3*kx],   a0);
          a1 = fmaf(w, f[3*kx+1], a1);
          a2 = fmaf(w, f[3*kx+2], a2);
          a3 = fmaf(w, f[3*kx+3], a3);
        }
      }
    }
    int z = zb + zl;
    int v = (z*DS + y)*DS + x0;
    A2th[(v+0)*CH + c] = (_Float16)(a0+bias);
    A2th[(v+1)*CH + c] = (_Float16)(a1+bias);
    A2th[(v+2)*CH + c] = (_Float16)(a2+bias);
    A2th[(v+3)*CH + c] = (_Float16)(a3+bias);
  }
}

// ---------------------------------------------------------------------------
// K4: offset conv, f16 MFMA, register-prefetch pipeline.  Per tap only LDS
// writes + MFMA sit between barriers; tap k+1's W and B (shifted rows) global
// loads are issued right after barrier1 and land during MFMA(k)+barrier2.
// 2 barriers/tap.  LDS 40 KB -> 4 blocks/CU.
// ---------------------------------------------------------------------------
__global__ __launch_bounds__(256) void offconv_kernel(
    const _Float16* __restrict__ A2th, const _Float16* __restrict__ WTh,
    _Float16* __restrict__ OFFp) {
  const int vb = (blockIdx.x % 216) * 64;
  const int kg = blockIdx.x / 216;          // 0..2
  __shared__ __align__(16) _Float16 Wl[96*128];  // 24 KB
  __shared__ __align__(16) _Float16 Bl[64*128];  // 16 KB
  const int t    = threadIdx.x;
  const int lane = t & 63, w = t >> 6;
  const int l16  = lane & 15, quad = lane >> 4;
  const int wo = t >> 4, wcg = t & 15;      // W-stage mapping (6 rows apart 16)
  const int cq = t & 15, vi0 = t >> 4;      // B-stage mapping
  // per-thread voxel coords (4 voxels, fixed across taps)
  int pvz[4], pvy[4], pvx[4], pvv[4];
  #pragma unroll
  for (int p = 0; p < 4; ++p) {
    int vl = (p << 4) + vi0;
    int v = vb + vl;
    pvv[p] = v; pvz[p] = v / HW; pvy[p] = (v / DS) % DS; pvx[p] = v % DS;
  }
  uint4 wregs[6], bregs[4];
  auto loadW = [&](int k) {
    #pragma unroll
    for (int i = 0; i < 6; ++i)
      wregs[i] = *(const uint4*)&WTh[(k*96 + wo + 16*i)*128 + (wcg << 3)];
  };
  auto loadB = [&](int k) {
    const int dz = k/9 - 1, dy = (k/3)%3 - 1, dx = k%3 - 1;
    const int doff = (dz*DS + dy)*DS + dx;
    #pragma unroll
    for (int p = 0; p < 4; ++p) {
      int zz = pvz[p] + dz, yy = pvy[p] + dy, xq = pvx[p] + dx;
      uint4 pk = {0u,0u,0u,0u};
      if ((unsigned)zz < 24u && (unsigned)yy < 24u && (unsigned)xq < 24u)
        pk = *(const uint4*)&A2th[(pvv[p] + doff)*CH + (cq << 3)];
      bregs[p] = pk;
    }
  };
  f32x4 acc[6];
  #pragma unroll
  for (int m = 0; m < 6; ++m) acc[m] = (f32x4){0.f,0.f,0.f,0.f};

  const int k0 = kg*9;
  loadW(k0); loadB(k0);
  for (int kk = 0; kk < 9; ++kk) {
    // phase1: LDS writes from regs (no global dependency)
    #pragma unroll
    for (int i = 0; i < 6; ++i) {
      int o = wo + 16*i;
      *(uint4*)&Wl[o*128 + ((wcg ^ (o & 15)) << 3)] = wregs[i];
    }
    #pragma unroll
    for (int p = 0; p < 4; ++p) {
      int vl = (p << 4) + vi0;
      *(uint4*)&Bl[vl*128 + ((cq ^ (vl & 15)) << 3)] = bregs[p];
    }
    __syncthreads();
    // phase2: issue next tap's loads, then MFMA on current LDS
    if (kk < 8) { loadW(k0 + kk + 1); loadB(k0 + kk + 1); }
    #pragma unroll
    for (int ks = 0; ks < 4; ++ks) {
      int gx = (((ks << 2) + quad) ^ l16) << 3;
      f16x8 b = *(const f16x8*)&Bl[((w << 4) + l16)*128 + gx];
      #pragma unroll
      for (int m = 0; m < 6; ++m) {
        f16x8 a = *(const f16x8*)&Wl[((m << 4) + l16)*128 + gx];
        acc[m] = __builtin_amdgcn_mfma_f32_16x16x32_f16(a, b, acc[m], 0, 0, 0);
      }
    }
    __syncthreads();   // MFMA done before next phase1 rewrites LDS
  }
  #pragma unroll
  for (int m = 0; m < 6; ++m)
    #pragma unroll
    for (int r = 0; r < 4; ++r) {
      int o = (m << 4) + (quad << 2) + r;
      if (o < 81)
        OFFp[(kg*81 + o)*VS + vb + (w << 4) + l16] = (_Float16)acc[m][r];
    }
}

// ---------------------------------------------------------------------------
// K5: deformable conv, f16 MFMA, register-prefetch pipeline.
// Per tap: ph1 [Wl write from regs; (kk==0: meta->M)] b1
//          ph2 [issue W(k+1)+OFFp(k+1) loads; gather via M -> Bl] b2
//          ph3 [MFMA; meta(k+1) from landed regs -> M] b3
// Only the gather's L2 latency stays exposed.  LDS 52 KB -> 3 blocks/CU.
// ---------------------------------------------------------------------------
__global__ __launch_bounds__(256) void deform_kernel(
    const _Float16* __restrict__ A2th, const _Float16* __restrict__ OFFp,
    const float* __restrict__ b_off, const _Float16* __restrict__ WDh,
    _Float16* __restrict__ D0, _Float16* __restrict__ D1,
    _Float16* __restrict__ D2) {
  const int vb = (blockIdx.x % 216) * 64;
  const int kg = blockIdx.x / 216;          // 0..2
  _Float16* DP = (kg == 0) ? D0 : (kg == 1) ? D1 : D2;
  __shared__ __align__(16) _Float16 Wl[128*128]; // 32 KB
  __shared__ __align__(16) _Float16 Bl[64*128];  // 16 KB
  __shared__ uint2 M[64][8];                     // 4 KB
  const int t    = threadIdx.x;
  const int lane = t & 63, w = t >> 6;
  const int l16  = lane & 15, quad = lane >> 4;
  const int wo = t >> 4, wcg = t & 15;
  const int cq = t & 15, vi0 = t >> 4;
  // meta voxel (4 threads per voxel, 2 corners each)
  const int mvl = t >> 2, mcp = t & 3;
  const int mv = vb + mvl;
  const int mz = mv / HW, my = (mv / DS) % DS, mx = mv % DS;

  uint4 wregs[8];
  _Float16 ofr[9];
  auto loadW = [&](int k) {
    #pragma unroll
    for (int i = 0; i < 8; ++i)
      wregs[i] = *(const uint4*)&WDh[(k*CH + wo + 16*i)*CH + (wcg << 3)];
  };
  auto loadOff = [&](int k) {
    #pragma unroll
    for (int a = 0; a < 3; ++a)
      #pragma unroll
      for (int p = 0; p < 3; ++p)
        ofr[a*3 + p] = OFFp[(81*p + 3*k + a)*VS + mv];
  };
  auto metaToM = [&](int k) {
    float po[3];
    #pragma unroll
    for (int a = 0; a < 3; ++a)
      po[a] = (float)ofr[a*3] + (float)ofr[a*3+1] + (float)ofr[a*3+2]
            + b_off[3*k + a];
    float cz = (float)(mz + k/9     - 1) + po[0];
    float cy = (float)(my + (k/3)%3 - 1) + po[1];
    float cx = (float)(mx + k%3     - 1) + po[2];
    float fz = floorf(cz), fy = floorf(cy), fx = floorf(cx);
    int iz = (int)fz, iy = (int)fy, ix = (int)fx;
    float rz = cz - fz, ry = cy - fy, rx = cx - fx;
    #pragma unroll
    for (int c2 = 0; c2 < 2; ++c2) {
      int corner = mcp*2 + c2;
      int ca = corner >> 2, cb = (corner >> 1) & 1, cc = corner & 1;
      int zi = iz + ca, yi = iy + cb, xi = ix + cc;
      float ww = (ca ? rz : 1.f-rz) * (cb ? ry : 1.f-ry) * (cc ? rx : 1.f-rx);
      bool valid = ((unsigned)zi < 24u) && ((unsigned)yi < 24u) && ((unsigned)xi < 24u);
      float wv = valid ? ww : 0.f;
      half2v wp = {(_Float16)wv, (_Float16)wv};
      int idx = valid ? (zi*DS + yi)*DS + xi : 0;
      M[mvl][corner] = make_uint2(h2u(wp), (unsigned)(idx << 7));
    }
  };
  f32x4 acc[2][4];
  #pragma unroll
  for (int i = 0; i < 2; ++i)
    #pragma unroll
    for (int n = 0; n < 4; ++n) acc[i][n] = (f32x4){0.f,0.f,0.f,0.f};

  const int k0 = kg*9;
  loadW(k0); loadOff(k0);
  for (int kk = 0; kk < 9; ++kk) {
    const int k = k0 + kk;
    // phase1
    #pragma unroll
    for (int i = 0; i < 8; ++i) {
      int o = wo + 16*i;
      *(uint4*)&Wl[o*128 + ((wcg ^ (o & 15)) << 3)] = wregs[i];
    }
    if (kk == 0) metaToM(k);
    __syncthreads();
    // phase2: prefetch next tap, then gather
    if (kk < 8) { loadW(k + 1); loadOff(k + 1); }
    #pragma unroll
    for (int p = 0; p < 4; ++p) {
      int vl = (p << 4) + vi0;
      half2v a0 = {(_Float16)0.f, (_Float16)0.f};
      half2v a1 = a0, a2 = a0, a3 = a0;
      #pragma unroll
      for (int corner = 0; corner < 8; ++corner) {
        uint2 m = M[vl][corner];
        half2v wp = u2h(m.x);
        uint4 g = *(const uint4*)&A2th[m.y + (cq << 3)];
        a0 += u2h(g.x) * wp;
        a1 += u2h(g.y) * wp;
        a2 += u2h(g.z) * wp;
        a3 += u2h(g.w) * wp;
      }
      uint4 pk = {h2u(a0), h2u(a1), h2u(a2), h2u(a3)};
      *(uint4*)&Bl[vl*128 + ((cq ^ (vl & 15)) << 3)] = pk;
    }
    __syncthreads();
    // phase3: MFMA + next meta
    #pragma unroll
    for (int ks = 0; ks < 4; ++ks) {
      int gx = (((ks << 2) + quad) ^ l16) << 3;
      f16x8 a0 = *(const f16x8*)&Wl[((w << 5) + l16)*128 + gx];
      f16x8 a1 = *(const f16x8*)&Wl[((w << 5) + 16 + l16)*128 + gx];
      #pragma unroll
      for (int n = 0; n < 4; ++n) {
        f16x8 b = *(const f16x8*)&Bl[((n << 4) + l16)*128 + gx];
        acc[0][n] = __builtin_amdgcn_mfma_f32_16x16x32_f16(a0, b, acc[0][n], 0, 0, 0);
        acc[1][n] = __builtin_amdgcn_mfma_f32_16x16x32_f16(a1, b, acc[1][n], 0, 0, 0);
      }
    }
    if (kk < 8) metaToM(k + 1);
    __syncthreads();   // Wl/Bl/M fully consumed before next iter rewrites
  }
  #pragma unroll
  for (int i = 0; i < 2; ++i)
    #pragma unroll
    for (int n = 0; n < 4; ++n)
      #pragma unroll
      for (int r = 0; r < 4; ++r) {
        int o = (w << 5) + (i << 4) + (quad << 2) + r;
        int v = vb + (n << 4) + l16;
        DP[o*VS + v] = (_Float16)acc[i][n][r];
      }
}

// ---------------------------------------------------------------------------
// K6: f16 MFMA 1x1x1 conv: Bl = D0+D1+D2+b_def (fp16), W1h[o][c] staged,
// epilogue: out = x * (acc + b1).  grid 216, LDS 48 KB.
// ---------------------------------------------------------------------------
__global__ __launch_bounds__(256) void pw_mul_kernel(
    const _Float16* __restrict__ D0, const _Float16* __restrict__ D1,
    const _Float16* __restrict__ D2, const float* __restrict__ b_def,
    const _Float16* __restrict__ W1h, const float* __restrict__ b1,
    const float* __restrict__ x, float* __restrict__ out) {
  const int vb = blockIdx.x * 64;
  __shared__ __align__(16) _Float16 Wl[128*128]; // 32 KB
  __shared__ __align__(16) _Float16 Bl[64*128];  // 16 KB
  const int t    = threadIdx.x;
  const int lane = t & 63, w = t >> 6;
  const int l16  = lane & 15, quad = lane >> 4;
  const int wo = t >> 4, wcg = t & 15;
  #pragma unroll
  for (int i = 0; i < 8; ++i) {
    int o = wo + 16*i;
    *(uint4*)&Wl[o*128 + ((wcg ^ (o & 15)) << 3)] =
        *(const uint4*)&W1h[o*128 + (wcg << 3)];
  }
  {
    const int vsq = t & 15;    // v = 4*vsq..4*vsq+3
    const int c0  = t >> 4;    // c = c0 + 16*i
    #pragma unroll
    for (int i = 0; i < 8; ++i) {
      int c = c0 + (i << 4);
      float bd = b_def[c];
      int base = c*VS + vb + (vsq << 2);
      h4 a0 = *(const h4*)&D0[base];
      h4 a1 = *(const h4*)&D1[base];
      h4 a2 = *(const h4*)&D2[base];
      #pragma unroll
      for (int j = 0; j < 4; ++j) {
        float s = (float)a0[j] + (float)a1[j] + (float)a2[j] + bd;
        int row = (vsq << 2) + j;
        Bl[row*128 + (((c >> 3) ^ (row & 15)) << 3) + (c & 7)] = (_Float16)s;
      }
    }
  }
  __syncthreads();
  f32x4 acc[2][4];
  #pragma unroll
  for (int i = 0; i < 2; ++i)
    #pragma unroll
    for (int n = 0; n < 4; ++n) acc[i][n] = (f32x4){0.f,0.f,0.f,0.f};
  #pragma unroll
  for (int ks = 0; ks < 4; ++ks) {
    int gx = (((ks << 2) + quad) ^ l16) << 3;
    f16x8 a0 = *(const f16x8*)&Wl[((w << 5) + l16)*128 + gx];
    f16x8 a1 = *(const f16x8*)&Wl[((w << 5) + 16 + l16)*128 + gx];
    #pragma unroll
    for (int n = 0; n < 4; ++n) {
      f16x8 b = *(const f16x8*)&Bl[((n << 4) + l16)*128 + gx];
      acc[0][n] = __builtin_amdgcn_mfma_f32_16x16x32_f16(a0, b, acc[0][n], 0, 0, 0);
      acc[1][n] = __builtin_amdgcn_mfma_f32_16x16x32_f16(a1, b, acc[1][n], 0, 0, 0);
    }
  }
  #pragma unroll
  for (int i = 0; i < 2; ++i)
    #pragma unroll
    for (int n = 0; n < 4; ++n)
      #pragma unroll
      for (int r = 0; r < 4; ++r) {
        int o = (w << 5) + (i << 4) + (quad << 2) + r;
        int v = vb + (n << 4) + l16;
        out[o*VS + v] = x[o*VS + v] * (acc[i][n][r] + b1[o]);
      }
}

// ---------------------------------------------------------------------------
// Workspace (floats, total 5,613,824 f = 22.5 MB):
//   [0        , 1769472)  A1 fp32 (dw5 out) -> later D0,D1 fp16
//   [1769472  , 2654208)  A2th [V][128] fp16
//   [2654208  , 4333824)  OFFp [3][81][V] fp16
//   [4333824  , 5218560)  D2 fp16
//   [5218560  , ...)      WTh fp16 | WDh fp16 | W1h fp16
// ---------------------------------------------------------------------------
extern "C" void kernel_launch(void* const* d_in, const int* in_sizes, int n_in,
                              void* d_out, int out_size, void* d_ws, size_t ws_size,
                              hipStream_t stream) {
  (void)in_sizes; (void)n_in; (void)out_size; (void)ws_size;
  const float* x     = (const float*)d_in[0];
  const float* w0    = (const float*)d_in[1];
  const float* b0    = (const float*)d_in[2];
  const float* wsw   = (const float*)d_in[3];
  const float* bs    = (const float*)d_in[4];
  const float* w_off = (const float*)d_in[5];
  const float* b_off = (const float*)d_in[6];
  const float* w_def = (const float*)d_in[7];
  const float* b_def = (const float*)d_in[8];
  const float* w1    = (const float*)d_in[9];
  const float* b1    = (const float*)d_in[10];
  float* out = (float*)d_out;

  float* wsf = (float*)d_ws;
  float*     A1   = wsf;
  _Float16*  A2th = (_Float16*)(wsf + 1769472);
  _Float16*  OFFp = (_Float16*)(wsf + 2654208);
  _Float16*  D2   = (_Float16*)(wsf + 4333824);
  _Float16*  WTh  = (_Float16*)(wsf + 5218560);
  _Float16*  WDh  = WTh + 331776;
  _Float16*  W1h  = WDh + 442368;
  _Float16*  D0   = (_Float16*)A1;          // A1 dead after dwdil
  _Float16*  D1   = D0 + 128*VS;

  prep_weights  <<<225, 256, 0, stream>>>(w_off, w_def, w1, WTh, WDh, W1h);
  dw5_kernel    <<<512, 256, 0, stream>>>(x, w0, b0, A1);
  dwdil_kernel  <<<512, 256, 0, stream>>>(A1, wsw, bs, A2th);
  offconv_kernel<<<648, 256, 0, stream>>>(A2th, WTh, OFFp);
  deform_kernel <<<648, 256, 0, stream>>>(A2th, OFFp, b_off, WDh, D0, D1, D2);
  pw_mul_kernel <<<216, 256, 0, stream>>>(D0, D1, D2, b_def, W1h, b1, x, out);
}

// Round 7
// 296.592 us; speedup vs baseline: 1.3774x; 1.3774x over previous
//
#include <hip/hip_runtime.h>

#define CH 128
#define DS 24
#define HW (DS*DS)      // 576
#define VS (DS*DS*DS)   // 13824

typedef _Float16 f16x8 __attribute__((ext_vector_type(8)));
typedef _Float16 half2v __attribute__((ext_vector_type(2)));
typedef __attribute__((ext_vector_type(4))) float f32x4;
typedef _Float16 h4 __attribute__((ext_vector_type(4)));

__device__ __forceinline__ half2v u2h(unsigned u) {
  union { unsigned u; half2v h; } v; v.u = u; return v.h;
}
__device__ __forceinline__ unsigned h2u(half2v h) {
  union { unsigned u; half2v h; } v; v.h = h; return v.u;
}

// async global->LDS DMA, 16B per lane; lds dest = wave-uniform base + lane*16
__device__ __forceinline__ void gld_lds16(const _Float16* g, _Float16* l) {
  __builtin_amdgcn_global_load_lds(
      (const __attribute__((address_space(1))) void*)g,
      (__attribute__((address_space(3))) void*)l, 16, 0, 0);
}

// sum of 3 fp16 offset partials + bias, row = 3*kn+a
__device__ __forceinline__ float off_sum(const _Float16* __restrict__ OFFp,
                                         const float* __restrict__ b_off,
                                         int kn, int a, int mv) {
  int row = 3*kn + a;
  return (float)OFFp[row*VS + mv] + (float)OFFp[(81 + row)*VS + mv]
       + (float)OFFp[(162 + row)*VS + mv] + b_off[row];
}

// compute this thread's 2 trilinear corners for tap kn -> Mrow[corner]
__device__ __forceinline__ void meta2(int kn, int mz, int my, int mx,
                                      float po0, float po1, float po2,
                                      int mcp, uint2* Mrow) {
  float cz = (float)(mz + kn/9     - 1) + po0;
  float cy = (float)(my + (kn/3)%3 - 1) + po1;
  float cx = (float)(mx + kn%3     - 1) + po2;
  float fz = floorf(cz), fy = floorf(cy), fx = floorf(cx);
  int iz = (int)fz, iy = (int)fy, ix = (int)fx;
  float rz = cz - fz, ry = cy - fy, rx = cx - fx;
  #pragma unroll
  for (int c2 = 0; c2 < 2; ++c2) {
    int corner = mcp*2 + c2;
    int ca = corner >> 2, cb = (corner >> 1) & 1, cc = corner & 1;
    int zi = iz + ca, yi = iy + cb, xi = ix + cc;
    float ww = (ca ? rz : 1.f-rz) * (cb ? ry : 1.f-ry) * (cc ? rx : 1.f-rx);
    bool valid = ((unsigned)zi < 24u) && ((unsigned)yi < 24u) && ((unsigned)xi < 24u);
    float wv = valid ? ww : 0.f;
    half2v wp = {(_Float16)wv, (_Float16)wv};
    int idx = valid ? (zi*DS + yi)*DS + xi : 0;
    Mrow[corner] = make_uint2(h2u(wp), (unsigned)(idx << 7));
  }
}

// ---------------------------------------------------------------------------
// K0: weight prep, coalesced via LDS transpose.
// ---------------------------------------------------------------------------
__global__ __launch_bounds__(256) void prep_weights(
    const float* __restrict__ w_off, const float* __restrict__ w_def,
    const float* __restrict__ w1,
    _Float16* __restrict__ WTh, _Float16* __restrict__ WDh,
    _Float16* __restrict__ W1h) {
  __shared__ float sbuf[3456];
  const int b = blockIdx.x, t = threadIdx.x;
  if (b < 96) {
    const int o = b;
    if (o < 81) {
      for (int s = t; s < 3456; s += 256) sbuf[s] = w_off[o*3456 + s];
      __syncthreads();
      for (int s = t; s < 3456; s += 256) {
        int k = s >> 7, c = s & 127;
        WTh[(k*96 + o)*128 + c] = (_Float16)sbuf[c*27 + k];
      }
    } else {
      for (int s = t; s < 3456; s += 256) {
        int k = s >> 7, c = s & 127;
        WTh[(k*96 + o)*128 + c] = (_Float16)0.f;
      }
    }
  } else if (b < 224) {
    const int o = b - 96;
    for (int s = t; s < 3456; s += 256) sbuf[s] = w_def[o*3456 + s];
    __syncthreads();
    for (int s = t; s < 3456; s += 256) {
      int k = s >> 7, c = s & 127;
      WDh[(k*128 + o)*128 + c] = (_Float16)sbuf[c*27 + k];
    }
  } else {
    for (int s = t; s < 16384; s += 256) W1h[s] = (_Float16)w1[s];
  }
}

// ---------------------------------------------------------------------------
// K1: depthwise 5x5x5, pad=2.
// ---------------------------------------------------------------------------
__global__ __launch_bounds__(256) void dw5_kernel(
    const float* __restrict__ x, const float* __restrict__ w0,
    const float* __restrict__ b0, float* __restrict__ A1) {
  const int c  = blockIdx.x >> 2;
  const int zb = (blockIdx.x & 3) * 6;
  __shared__ __align__(16) float sin_[10*24*36];
  __shared__ float sw[128];
  const int t = threadIdx.x;
  if (t < 125) sw[t] = w0[c*125 + t];
  const float* xc = x + c*VS;
  for (int i = t; i < 10*24*36; i += 256) {
    int px = i % 36;
    int y  = (i / 36) % 24;
    int pz = i / (36*24);
    int xx = px - 2;
    int zz = zb - 2 + pz;
    float v = 0.f;
    if ((unsigned)xx < 24u && (unsigned)zz < 24u) v = xc[zz*HW + y*DS + xx];
    sin_[i] = v;
  }
  __syncthreads();
  const float bias = b0[c];
  for (int g = t; g < 6*24*6; g += 256) {
    int xg = g % 6;
    int y  = (g / 6) % 24;
    int zl = g / 144;
    int x0 = xg * 4;
    float a0=0.f, a1=0.f, a2=0.f, a3=0.f;
    for (int kz = 0; kz < 5; ++kz) {
      int pz = zl + kz;
      for (int ky = 0; ky < 5; ++ky) {
        int yy = y + ky - 2;
        if ((unsigned)yy >= 24u) continue;
        const float* row = &sin_[(pz*24 + yy)*36 + x0];
        float4 r0 = *(const float4*)(row);
        float4 r1 = *(const float4*)(row+4);
        float4 r2 = *(const float4*)(row+8);
        float f[12] = {r0.x,r0.y,r0.z,r0.w, r1.x,r1.y,r1.z,r1.w,
                       r2.x,r2.y,r2.z,r2.w};
        const float* wr = &sw[(kz*5+ky)*5];
        #pragma unroll
        for (int kx = 0; kx < 5; ++kx) {
          float w = wr[kx];
          a0 = fmaf(w, f[kx],   a0);
          a1 = fmaf(w, f[kx+1], a1);
          a2 = fmaf(w, f[kx+2], a2);
          a3 = fmaf(w, f[kx+3], a3);
        }
      }
    }
    int z = zb + zl;
    int v = (z*DS + y)*DS + x0;
    *(float4*)&A1[c*VS + v] = make_float4(a0+bias, a1+bias, a2+bias, a3+bias);
  }
}

// ---------------------------------------------------------------------------
// K2: depthwise 5x5x5 dil=3 pad=6 + fused transpose to A2th[v][128 c] fp16.
// ---------------------------------------------------------------------------
__global__ __launch_bounds__(256) void dwdil_kernel(
    const float* __restrict__ A1, const float* __restrict__ wgt,
    const float* __restrict__ bs, _Float16* __restrict__ A2th) {
  const int c  = blockIdx.x >> 2;
  const int zb = (blockIdx.x & 3) * 6;
  __shared__ __align__(16) float sin_[18*24*36];
  __shared__ float sw[128];
  const int t = threadIdx.x;
  if (t < 125) sw[t] = wgt[c*125 + t];
  const float* xc = A1 + c*VS;
  for (int i = t; i < 18*24*36; i += 256) {
    int px = i % 36;
    int y  = (i / 36) % 24;
    int pz = i / (36*24);
    int xx = px - 6;
    int zz = zb - 6 + pz;
    float v = 0.f;
    if ((unsigned)xx < 24u && (unsigned)zz < 24u) v = xc[zz*HW + y*DS + xx];
    sin_[i] = v;
  }
  __syncthreads();
  const float bias = bs[c];
  for (int g = t; g < 6*24*6; g += 256) {
    int xg = g % 6;
    int y  = (g / 6) % 24;
    int zl = g / 144;   // 0..5
    int x0 = xg * 4;
    float a0=0.f, a1=0.f, a2=0.f, a3=0.f;
    for (int kz = 0; kz < 5; ++kz) {
      int pz = zl + 3*kz;
      for (int ky = 0; ky < 5; ++ky) {
        int yy = y + 3*ky - 6;
        if ((unsigned)yy >= 24u) continue;
        const float* row = &sin_[(pz*24 + yy)*36 + x0];
        float4 r0 = *(const float4*)(row);
        float4 r1 = *(const float4*)(row+4);
        float4 r2 = *(const float4*)(row+8);
        float4 r3 = *(const float4*)(row+12);
        float f[16] = {r0.x,r0.y,r0.z,r0.w, r1.x,r1.y,r1.z,r1.w,
                       r2.x,r2.y,r2.z,r2.w, r3.x,r3.y,r3.z,r3.w};
        const float* wr = &sw[(kz*5+ky)*5];
        #pragma unroll
        for (int kx = 0; kx < 5; ++kx) {
          float w = wr[kx];
          a0 = fmaf(w, f[3*kx],   a0);
          a1 = fmaf(w, f[3*kx+1], a1);
          a2 = fmaf(w, f[3*kx+2], a2);
          a3 = fmaf(w, f[3*kx+3], a3);
        }
      }
    }
    int z = zb + zl;
    int v = (z*DS + y)*DS + x0;
    A2th[(v+0)*CH + c] = (_Float16)(a0+bias);
    A2th[(v+1)*CH + c] = (_Float16)(a1+bias);
    A2th[(v+2)*CH + c] = (_Float16)(a2+bias);
    A2th[(v+3)*CH + c] = (_Float16)(a3+bias);
  }
}

// ---------------------------------------------------------------------------
// K4: offset conv, f16 MFMA.  W staged per tap via async global_load_lds
// (source-side XOR swizzle; LDS dest is wave-uniform base + lane*16).
// B loaded to regs (border-masked) then written to Bl.  The DMA drains at
// the barrier -> W latency hidden behind B loads.  LDS 40KB -> 4 blocks/CU.
// ---------------------------------------------------------------------------
__global__ __launch_bounds__(256, 4) void offconv_kernel(
    const _Float16* __restrict__ A2th, const _Float16* __restrict__ WTh,
    _Float16* __restrict__ OFFp) {
  const int vb = (blockIdx.x % 216) * 64;
  const int kg = blockIdx.x / 216;          // 0..2
  __shared__ __align__(16) _Float16 Wl[96*128];  // 24 KB
  __shared__ __align__(16) _Float16 Bl[64*128];  // 16 KB
  const int t    = threadIdx.x;
  const int lane = t & 63, w = t >> 6;
  const int l16  = lane & 15, quad = lane >> 4;
  const int cq = t & 15, vi0 = t >> 4;
  int pvz[4], pvy[4], pvx[4], pvv[4];
  #pragma unroll
  for (int p = 0; p < 4; ++p) {
    int vl = (p << 4) + vi0;
    int v = vb + vl;
    pvv[p] = v; pvz[p] = v / HW; pvy[p] = (v / DS) % DS; pvx[p] = v % DS;
  }
  const int wrow = (lane >> 4);             // row within 4-row DMA block
  f32x4 acc[6];
  #pragma unroll
  for (int m = 0; m < 6; ++m) acc[m] = (f32x4){0.f,0.f,0.f,0.f};

  const int k0 = kg*9;
  for (int kk = 0; kk < 9; ++kk) {
    const int k = k0 + kk;
    // async W DMA: 6 x (4 rows x 16 colblocks) per wave
    #pragma unroll
    for (int i = 0; i < 6; ++i) {
      int o = 16*i + 4*w + wrow;
      const _Float16* g = &WTh[(k*96 + o)*128 + ((l16 ^ (o & 15)) << 3)];
      gld_lds16(g, &Wl[(16*i + 4*w)*128]);
    }
    // B: shifted rows, border-masked, regs then LDS
    const int dz = k/9 - 1, dy = (k/3)%3 - 1, dx = k%3 - 1;
    const int doff = (dz*DS + dy)*DS + dx;
    uint4 br[4];
    #pragma unroll
    for (int p = 0; p < 4; ++p) {
      int zz = pvz[p] + dz, yy = pvy[p] + dy, xq = pvx[p] + dx;
      uint4 pk = {0u,0u,0u,0u};
      if ((unsigned)zz < 24u && (unsigned)yy < 24u && (unsigned)xq < 24u)
        pk = *(const uint4*)&A2th[(pvv[p] + doff)*CH + (cq << 3)];
      br[p] = pk;
    }
    #pragma unroll
    for (int p = 0; p < 4; ++p) {
      int vl = (p << 4) + vi0;
      *(uint4*)&Bl[vl*128 + ((cq ^ (vl & 15)) << 3)] = br[p];
    }
    __syncthreads();                          // W DMA + Bl writes complete
    #pragma unroll
    for (int ks = 0; ks < 4; ++ks) {
      int gx = (((ks << 2) + quad) ^ l16) << 3;
      f16x8 b = *(const f16x8*)&Bl[((w << 4) + l16)*128 + gx];
      #pragma unroll
      for (int m = 0; m < 6; ++m) {
        f16x8 a = *(const f16x8*)&Wl[((m << 4) + l16)*128 + gx];
        acc[m] = __builtin_amdgcn_mfma_f32_16x16x32_f16(a, b, acc[m], 0, 0, 0);
      }
    }
    __syncthreads();                          // LDS consumed before restage
  }
  #pragma unroll
  for (int m = 0; m < 6; ++m)
    #pragma unroll
    for (int r = 0; r < 4; ++r) {
      int o = (m << 4) + (quad << 2) + r;
      if (o < 81)
        OFFp[(kg*81 + o)*VS + vb + (w << 4) + l16] = (_Float16)acc[m][r];
    }
}

// ---------------------------------------------------------------------------
// K5: deformable conv, f16 MFMA, NO W LDS: each lane loads its 8 A-fragments
// straight from WDh (fragment layout A[m=lane&15][c=ks*32+quad*8], 16B).
// Issued before the gather so their latency is covered by the gather's own
// vmcnt waits.  Meta double-buffered in LDS (M[2]); 2 barriers/tap.
// LDS 24KB; launch_bounds(256,4) caps VGPR at 128.
// ---------------------------------------------------------------------------
__global__ __launch_bounds__(256, 4) void deform_kernel(
    const _Float16* __restrict__ A2th, const _Float16* __restrict__ OFFp,
    const float* __restrict__ b_off, const _Float16* __restrict__ WDh,
    _Float16* __restrict__ D0, _Float16* __restrict__ D1,
    _Float16* __restrict__ D2) {
  const int vb = (blockIdx.x % 216) * 64;
  const int kg = blockIdx.x / 216;          // 0..2
  _Float16* DP = (kg == 0) ? D0 : (kg == 1) ? D1 : D2;
  __shared__ __align__(16) _Float16 Bl[64*128];  // 16 KB
  __shared__ uint2 M[2][64][8];                  // 8 KB
  const int t    = threadIdx.x;
  const int lane = t & 63, w = t >> 6;
  const int l16  = lane & 15, quad = lane >> 4;
  const int cq = t & 15, vi0 = t >> 4;
  const int mvl = t >> 2, mcp = t & 3;
  const int mv = vb + mvl;
  const int mz = mv / HW, my = (mv / DS) % DS, mx = mv % DS;

  f32x4 acc[2][4];
  #pragma unroll
  for (int i = 0; i < 2; ++i)
    #pragma unroll
    for (int n = 0; n < 4; ++n) acc[i][n] = (f32x4){0.f,0.f,0.f,0.f};

  const int k0 = kg*9;
  {  // prologue: meta(k0) -> M[0]
    float po0 = off_sum(OFFp, b_off, k0, 0, mv);
    float po1 = off_sum(OFFp, b_off, k0, 1, mv);
    float po2 = off_sum(OFFp, b_off, k0, 2, mv);
    meta2(k0, mz, my, mx, po0, po1, po2, mcp, &M[0][mvl][0]);
  }
  __syncthreads();

  for (int kk = 0; kk < 9; ++kk) {
    const int k = k0 + kk;
    const int buf = kk & 1;
    // A-fragments direct from global (issued first; covered by gather waits)
    f16x8 af0[4], af1[4];
    #pragma unroll
    for (int ks = 0; ks < 4; ++ks) {
      af0[ks] = *(const f16x8*)&WDh[(k*CH + (w<<5) + l16)*CH + (ks<<5) + (quad<<3)];
      af1[ks] = *(const f16x8*)&WDh[(k*CH + (w<<5) + 16 + l16)*CH + (ks<<5) + (quad<<3)];
    }
    // next tap's offsets
    float po0 = 0.f, po1 = 0.f, po2 = 0.f;
    if (kk < 8) {
      po0 = off_sum(OFFp, b_off, k + 1, 0, mv);
      po1 = off_sum(OFFp, b_off, k + 1, 1, mv);
      po2 = off_sum(OFFp, b_off, k + 1, 2, mv);
    }
    // gather via M[buf] -> Bl
    #pragma unroll
    for (int p = 0; p < 4; ++p) {
      int vl = (p << 4) + vi0;
      half2v a0 = {(_Float16)0.f, (_Float16)0.f};
      half2v a1 = a0, a2 = a0, a3 = a0;
      #pragma unroll
      for (int corner = 0; corner < 8; ++corner) {
        uint2 m = M[buf][vl][corner];
        half2v wp = u2h(m.x);
        uint4 g = *(const uint4*)&A2th[m.y + (cq << 3)];
        a0 += u2h(g.x) * wp;
        a1 += u2h(g.y) * wp;
        a2 += u2h(g.z) * wp;
        a3 += u2h(g.w) * wp;
      }
      uint4 pk = {h2u(a0), h2u(a1), h2u(a2), h2u(a3)};
      *(uint4*)&Bl[vl*128 + ((cq ^ (vl & 15)) << 3)] = pk;
    }
    // meta(k+1) -> M[buf^1]
    if (kk < 8)
      meta2(k + 1, mz, my, mx, po0, po1, po2, mcp, &M[buf ^ 1][mvl][0]);
    __syncthreads();                          // Bl + M ready
    #pragma unroll
    for (int ks = 0; ks < 4; ++ks) {
      int gx = (((ks << 2) + quad) ^ l16) << 3;
      #pragma unroll
      for (int n = 0; n < 4; ++n) {
        f16x8 b = *(const f16x8*)&Bl[((n << 4) + l16)*128 + gx];
        acc[0][n] = __builtin_amdgcn_mfma_f32_16x16x32_f16(af0[ks], b, acc[0][n], 0, 0, 0);
        acc[1][n] = __builtin_amdgcn_mfma_f32_16x16x32_f16(af1[ks], b, acc[1][n], 0, 0, 0);
      }
    }
    __syncthreads();                          // Bl consumed before restage
  }
  #pragma unroll
  for (int i = 0; i < 2; ++i)
    #pragma unroll
    for (int n = 0; n < 4; ++n)
      #pragma unroll
      for (int r = 0; r < 4; ++r) {
        int o = (w << 5) + (i << 4) + (quad << 2) + r;
        int v = vb + (n << 4) + l16;
        DP[o*VS + v] = (_Float16)acc[i][n][r];
      }
}

// ---------------------------------------------------------------------------
// K6: f16 MFMA 1x1x1 conv: Bl = D0+D1+D2+b_def (fp16), W1h staged,
// epilogue: out = x * (acc + b1).  grid 216.
// ---------------------------------------------------------------------------
__global__ __launch_bounds__(256) void pw_mul_kernel(
    const _Float16* __restrict__ D0, const _Float16* __restrict__ D1,
    const _Float16* __restrict__ D2, const float* __restrict__ b_def,
    const _Float16* __restrict__ W1h, const float* __restrict__ b1,
    const float* __restrict__ x, float* __restrict__ out) {
  const int vb = blockIdx.x * 64;
  __shared__ __align__(16) _Float16 Wl[128*128]; // 32 KB
  __shared__ __align__(16) _Float16 Bl[64*128];  // 16 KB
  const int t    = threadIdx.x;
  const int lane = t & 63, w = t >> 6;
  const int l16  = lane & 15, quad = lane >> 4;
  const int wo = t >> 4, wcg = t & 15;
  #pragma unroll
  for (int i = 0; i < 8; ++i) {
    int o = wo + 16*i;
    *(uint4*)&Wl[o*128 + ((wcg ^ (o & 15)) << 3)] =
        *(const uint4*)&W1h[o*128 + (wcg << 3)];
  }
  {
    const int vsq = t & 15;    // v = 4*vsq..4*vsq+3
    const int c0  = t >> 4;    // c = c0 + 16*i
    #pragma unroll
    for (int i = 0; i < 8; ++i) {
      int c = c0 + (i << 4);
      float bd = b_def[c];
      int base = c*VS + vb + (vsq << 2);
      h4 a0 = *(const h4*)&D0[base];
      h4 a1 = *(const h4*)&D1[base];
      h4 a2 = *(const h4*)&D2[base];
      #pragma unroll
      for (int j = 0; j < 4; ++j) {
        float s = (float)a0[j] + (float)a1[j] + (float)a2[j] + bd;
        int row = (vsq << 2) + j;
        Bl[row*128 + (((c >> 3) ^ (row & 15)) << 3) + (c & 7)] = (_Float16)s;
      }
    }
  }
  __syncthreads();
  f32x4 acc[2][4];
  #pragma unroll
  for (int i = 0; i < 2; ++i)
    #pragma unroll
    for (int n = 0; n < 4; ++n) acc[i][n] = (f32x4){0.f,0.f,0.f,0.f};
  #pragma unroll
  for (int ks = 0; ks < 4; ++ks) {
    int gx = (((ks << 2) + quad) ^ l16) << 3;
    f16x8 a0 = *(const f16x8*)&Wl[((w << 5) + l16)*128 + gx];
    f16x8 a1 = *(const f16x8*)&Wl[((w << 5) + 16 + l16)*128 + gx];
    #pragma unroll
    for (int n = 0; n < 4; ++n) {
      f16x8 b = *(const f16x8*)&Bl[((n << 4) + l16)*128 + gx];
      acc[0][n] = __builtin_amdgcn_mfma_f32_16x16x32_f16(a0, b, acc[0][n], 0, 0, 0);
      acc[1][n] = __builtin_amdgcn_mfma_f32_16x16x32_f16(a1, b, acc[1][n], 0, 0, 0);
    }
  }
  #pragma unroll
  for (int i = 0; i < 2; ++i)
    #pragma unroll
    for (int n = 0; n < 4; ++n)
      #pragma unroll
      for (int r = 0; r < 4; ++r) {
        int o = (w << 5) + (i << 4) + (quad << 2) + r;
        int v = vb + (n << 4) + l16;
        out[o*VS + v] = x[o*VS + v] * (acc[i][n][r] + b1[o]);
      }
}

// ---------------------------------------------------------------------------
// Workspace (floats, total 5,613,824 f = 22.5 MB):
//   [0        , 1769472)  A1 fp32 (dw5 out) -> later D0,D1 fp16
//   [1769472  , 2654208)  A2th [V][128] fp16
//   [2654208  , 4333824)  OFFp [3][81][V] fp16
//   [4333824  , 5218560)  D2 fp16
//   [5218560  , ...)      WTh fp16 | WDh fp16 | W1h fp16
// ---------------------------------------------------------------------------
extern "C" void kernel_launch(void* const* d_in, const int* in_sizes, int n_in,
                              void* d_out, int out_size, void* d_ws, size_t ws_size,
                              hipStream_t stream) {
  (void)in_sizes; (void)n_in; (void)out_size; (void)ws_size;
  const float* x     = (const float*)d_in[0];
  const float* w0    = (const float*)d_in[1];
  const float* b0    = (const float*)d_in[2];
  const float* wsw   = (const float*)d_in[3];
  const float* bs    = (const float*)d_in[4];
  const float* w_off = (const float*)d_in[5];
  const float* b_off = (const float*)d_in[6];
  const float* w_def = (const float*)d_in[7];
  const float* b_def = (const float*)d_in[8];
  const float* w1    = (const float*)d_in[9];
  const float* b1    = (const float*)d_in[10];
  float* out = (float*)d_out;

  float* wsf = (float*)d_ws;
  float*     A1   = wsf;
  _Float16*  A2th = (_Float16*)(wsf + 1769472);
  _Float16*  OFFp = (_Float16*)(wsf + 2654208);
  _Float16*  D2   = (_Float16*)(wsf + 4333824);
  _Float16*  WTh  = (_Float16*)(wsf + 5218560);
  _Float16*  WDh  = WTh + 331776;
  _Float16*  W1h  = WDh + 442368;
  _Float16*  D0   = (_Float16*)A1;          // A1 dead after dwdil
  _Float16*  D1   = D0 + 128*VS;

  prep_weights  <<<225, 256, 0, stream>>>(w_off, w_def, w1, WTh, WDh, W1h);
  dw5_kernel    <<<512, 256, 0, stream>>>(x, w0, b0, A1);
  dwdil_kernel  <<<512, 256, 0, stream>>>(A1, wsw, bs, A2th);
  offconv_kernel<<<648, 256, 0, stream>>>(A2th, WTh, OFFp);
  deform_kernel <<<648, 256, 0, stream>>>(A2th, OFFp, b_off, WDh, D0, D1, D2);
  pw_mul_kernel <<<216, 256, 0, stream>>>(D0, D1, D2, b_def, W1h, b1, x, out);
}

// Round 8
// 296.562 us; speedup vs baseline: 1.3775x; 1.0001x over previous
//
#include <hip/hip_runtime.h>

#define CH 128
#define DS 24
#define HW (DS*DS)      // 576
#define VS (DS*DS*DS)   // 13824

typedef _Float16 f16x8 __attribute__((ext_vector_type(8)));
typedef _Float16 half2v __attribute__((ext_vector_type(2)));
typedef __attribute__((ext_vector_type(4))) float f32x4;
typedef _Float16 h4 __attribute__((ext_vector_type(4)));

__device__ __forceinline__ half2v u2h(unsigned u) {
  union { unsigned u; half2v h; } v; v.u = u; return v.h;
}
__device__ __forceinline__ unsigned h2u(half2v h) {
  union { unsigned u; half2v h; } v; v.h = h; return v.u;
}

// sum of 3 fp16 offset partials + bias, row = 3*kn+a
__device__ __forceinline__ float off_sum(const _Float16* __restrict__ OFFp,
                                         const float* __restrict__ b_off,
                                         int kn, int a, int mv) {
  int row = 3*kn + a;
  return (float)OFFp[row*VS + mv] + (float)OFFp[(81 + row)*VS + mv]
       + (float)OFFp[(162 + row)*VS + mv] + b_off[row];
}

// this thread's 2 trilinear corners for tap kn -> Mrow[corner]
__device__ __forceinline__ void meta2(int kn, int mz, int my, int mx,
                                      float po0, float po1, float po2,
                                      int mcp, uint2* Mrow) {
  float cz = (float)(mz + kn/9     - 1) + po0;
  float cy = (float)(my + (kn/3)%3 - 1) + po1;
  float cx = (float)(mx + kn%3     - 1) + po2;
  float fz = floorf(cz), fy = floorf(cy), fx = floorf(cx);
  int iz = (int)fz, iy = (int)fy, ix = (int)fx;
  float rz = cz - fz, ry = cy - fy, rx = cx - fx;
  #pragma unroll
  for (int c2 = 0; c2 < 2; ++c2) {
    int corner = mcp*2 + c2;
    int ca = corner >> 2, cb = (corner >> 1) & 1, cc = corner & 1;
    int zi = iz + ca, yi = iy + cb, xi = ix + cc;
    float ww = (ca ? rz : 1.f-rz) * (cb ? ry : 1.f-ry) * (cc ? rx : 1.f-rx);
    bool valid = ((unsigned)zi < 24u) && ((unsigned)yi < 24u) && ((unsigned)xi < 24u);
    float wv = valid ? ww : 0.f;
    half2v wp = {(_Float16)wv, (_Float16)wv};
    int idx = valid ? (zi*DS + yi)*DS + xi : 0;
    Mrow[corner] = make_uint2(h2u(wp), (unsigned)(idx << 7));
  }
}

// gather one tap's 64x128 B-tile into BlBuf using meta Mb
__device__ __forceinline__ void gather_tap(
    const _Float16* __restrict__ A2th, const uint2 (*Mb)[8],
    _Float16* BlBuf, int cq, int vi0) {
  #pragma unroll
  for (int p = 0; p < 4; ++p) {
    int vl = (p << 4) + vi0;
    half2v a0 = {(_Float16)0.f, (_Float16)0.f};
    half2v a1 = a0, a2 = a0, a3 = a0;
    #pragma unroll
    for (int corner = 0; corner < 8; ++corner) {
      uint2 m = Mb[vl][corner];
      half2v wp = u2h(m.x);
      uint4 g = *(const uint4*)&A2th[m.y + (cq << 3)];
      a0 += u2h(g.x) * wp;
      a1 += u2h(g.y) * wp;
      a2 += u2h(g.z) * wp;
      a3 += u2h(g.w) * wp;
    }
    uint4 pk = {h2u(a0), h2u(a1), h2u(a2), h2u(a3)};
    *(uint4*)&BlBuf[vl*128 + ((cq ^ (vl & 15)) << 3)] = pk;
  }
}

// offconv B chunk: masked shifted-row load / swizzled store
__device__ __forceinline__ uint4 ld_chunk(const _Float16* __restrict__ A2th,
                                          int vb, int s, int k) {
  int vl = s >> 4, cq = s & 15;
  int v = vb + vl;
  int z = v / HW, y = (v / DS) % DS, xx = v % DS;
  int dz = k/9 - 1, dy = (k/3)%3 - 1, dx = k%3 - 1;
  uint4 pk = {0u,0u,0u,0u};
  int zz = z + dz, yy = y + dy, xq = xx + dx;
  if ((unsigned)zz < 24u && (unsigned)yy < 24u && (unsigned)xq < 24u)
    pk = *(const uint4*)&A2th[(v + (dz*DS + dy)*DS + dx)*CH + (cq << 3)];
  return pk;
}
__device__ __forceinline__ void st_chunk(_Float16* Bb, int s, uint4 pk) {
  int vl = s >> 4, cq = s & 15;
  *(uint4*)&Bb[vl*128 + ((cq ^ (vl & 15)) << 3)] = pk;
}

// ---------------------------------------------------------------------------
// K0: weight prep, coalesced via LDS transpose.
// ---------------------------------------------------------------------------
__global__ __launch_bounds__(256) void prep_weights(
    const float* __restrict__ w_off, const float* __restrict__ w_def,
    const float* __restrict__ w1,
    _Float16* __restrict__ WTh, _Float16* __restrict__ WDh,
    _Float16* __restrict__ W1h) {
  __shared__ float sbuf[3456];
  const int b = blockIdx.x, t = threadIdx.x;
  if (b < 96) {
    const int o = b;
    if (o < 81) {
      for (int s = t; s < 3456; s += 256) sbuf[s] = w_off[o*3456 + s];
      __syncthreads();
      for (int s = t; s < 3456; s += 256) {
        int k = s >> 7, c = s & 127;
        WTh[(k*96 + o)*128 + c] = (_Float16)sbuf[c*27 + k];
      }
    } else {
      for (int s = t; s < 3456; s += 256) {
        int k = s >> 7, c = s & 127;
        WTh[(k*96 + o)*128 + c] = (_Float16)0.f;
      }
    }
  } else if (b < 224) {
    const int o = b - 96;
    for (int s = t; s < 3456; s += 256) sbuf[s] = w_def[o*3456 + s];
    __syncthreads();
    for (int s = t; s < 3456; s += 256) {
      int k = s >> 7, c = s & 127;
      WDh[(k*128 + o)*128 + c] = (_Float16)sbuf[c*27 + k];
    }
  } else {
    for (int s = t; s < 16384; s += 256) W1h[s] = (_Float16)w1[s];
  }
}

// ---------------------------------------------------------------------------
// K1: depthwise 5x5x5, pad=2.  Block per (channel, z-triple of 8).
// Slab 7 planes (24.7 KB) -> 4+ blocks/CU, grid 1024.
// ---------------------------------------------------------------------------
__global__ __launch_bounds__(256) void dw5_kernel(
    const float* __restrict__ x, const float* __restrict__ w0,
    const float* __restrict__ b0, float* __restrict__ A1) {
  const int c  = blockIdx.x >> 3;
  const int zb = (blockIdx.x & 7) * 3;
  __shared__ __align__(16) float sin_[7*24*36];
  __shared__ float sw[128];
  const int t = threadIdx.x;
  if (t < 125) sw[t] = w0[c*125 + t];
  const float* xc = x + c*VS;
  for (int i = t; i < 7*24*36; i += 256) {
    int px = i % 36;
    int y  = (i / 36) % 24;
    int pz = i / (36*24);
    int xx = px - 2;
    int zz = zb - 2 + pz;
    float v = 0.f;
    if ((unsigned)xx < 24u && (unsigned)zz < 24u) v = xc[zz*HW + y*DS + xx];
    sin_[i] = v;
  }
  __syncthreads();
  const float bias = b0[c];
  for (int g = t; g < 3*24*6; g += 256) {
    int xg = g % 6;
    int y  = (g / 6) % 24;
    int zl = g / 144;    // 0..2
    int x0 = xg * 4;
    float a0=0.f, a1=0.f, a2=0.f, a3=0.f;
    for (int kz = 0; kz < 5; ++kz) {
      int pz = zl + kz;
      for (int ky = 0; ky < 5; ++ky) {
        int yy = y + ky - 2;
        if ((unsigned)yy >= 24u) continue;
        const float* row = &sin_[(pz*24 + yy)*36 + x0];
        float4 r0 = *(const float4*)(row);
        float4 r1 = *(const float4*)(row+4);
        float4 r2 = *(const float4*)(row+8);
        float f[12] = {r0.x,r0.y,r0.z,r0.w, r1.x,r1.y,r1.z,r1.w,
                       r2.x,r2.y,r2.z,r2.w};
        const float* wr = &sw[(kz*5+ky)*5];
        #pragma unroll
        for (int kx = 0; kx < 5; ++kx) {
          float w = wr[kx];
          a0 = fmaf(w, f[kx],   a0);
          a1 = fmaf(w, f[kx+1], a1);
          a2 = fmaf(w, f[kx+2], a2);
          a3 = fmaf(w, f[kx+3], a3);
        }
      }
    }
    int z = zb + zl;
    int v = (z*DS + y)*DS + x0;
    *(float4*)&A1[c*VS + v] = make_float4(a0+bias, a1+bias, a2+bias, a3+bias);
  }
}

// ---------------------------------------------------------------------------
// K2: depthwise 5x5x5 dil=3 pad=6 via mod-3 residue classes: dilated z-taps
// stay within a residue class, so a block stages only 8 stride-3 planes
// (27.6 KB) for 4 output planes.  grid = 128 ch x 3 residues x 2 halves.
// Fused transpose out: A2th[v][128 c] fp16.
// ---------------------------------------------------------------------------
__global__ __launch_bounds__(256) void dwdil_kernel(
    const float* __restrict__ A1, const float* __restrict__ wgt,
    const float* __restrict__ bs, _Float16* __restrict__ A2th) {
  const int c  = blockIdx.x / 6;
  const int rs = blockIdx.x % 6;
  const int r  = rs >> 1, s = rs & 1;
  const int zlo = r + 12*s - 6;           // slab plane p -> global z = zlo+3p
  __shared__ __align__(16) float sin_[8*24*36];
  __shared__ float sw[128];
  const int t = threadIdx.x;
  if (t < 125) sw[t] = wgt[c*125 + t];
  const float* xc = A1 + c*VS;
  for (int i = t; i < 8*24*36; i += 256) {
    int px = i % 36;
    int y  = (i / 36) % 24;
    int pz = i / (36*24);
    int xx = px - 6;
    int zz = zlo + 3*pz;
    float v = 0.f;
    if ((unsigned)xx < 24u && (unsigned)zz < 24u) v = xc[zz*HW + y*DS + xx];
    sin_[i] = v;
  }
  __syncthreads();
  const float bias = bs[c];
  for (int g = t; g < 4*24*6; g += 256) {
    int xg = g % 6;
    int y  = (g / 6) % 24;
    int j  = g / 144;   // 0..3
    int x0 = xg * 4;
    float a0=0.f, a1=0.f, a2=0.f, a3=0.f;
    for (int kz = 0; kz < 5; ++kz) {
      int pz = j + kz;                     // slab plane of z-6+3kz
      for (int ky = 0; ky < 5; ++ky) {
        int yy = y + 3*ky - 6;
        if ((unsigned)yy >= 24u) continue;
        const float* row = &sin_[(pz*24 + yy)*36 + x0];
        float4 r0 = *(const float4*)(row);
        float4 r1 = *(const float4*)(row+4);
        float4 r2 = *(const float4*)(row+8);
        float4 r3 = *(const float4*)(row+12);
        float f[16] = {r0.x,r0.y,r0.z,r0.w, r1.x,r1.y,r1.z,r1.w,
                       r2.x,r2.y,r2.z,r2.w, r3.x,r3.y,r3.z,r3.w};
        const float* wr = &sw[(kz*5+ky)*5];
        #pragma unroll
        for (int kx = 0; kx < 5; ++kx) {
          float w = wr[kx];
          a0 = fmaf(w, f[3*kx],   a0);
          a1 = fmaf(w, f[3*kx+1], a1);
          a2 = fmaf(w, f[3*kx+2], a2);
          a3 = fmaf(w, f[3*kx+3], a3);
        }
      }
    }
    int z = r + 12*s + 3*j;
    int v = (z*DS + y)*DS + x0;
    A2th[(v+0)*CH + c] = (_Float16)(a0+bias);
    A2th[(v+1)*CH + c] = (_Float16)(a1+bias);
    A2th[(v+2)*CH + c] = (_Float16)(a2+bias);
    A2th[(v+3)*CH + c] = (_Float16)(a3+bias);
  }
}

// ---------------------------------------------------------------------------
// K4: offset conv, f16 MFMA, 384-thread/6-wave blocks (wave = m-tile, A-frags
// direct from global -> no Wl, no redundancy).  Double-buffered Bl, single
// barrier per tap: [af(k) issue][B(k+1) loads][MFMA(k)][B(k+1) -> Bl] bar.
// LDS 32 KB.
// ---------------------------------------------------------------------------
__global__ __launch_bounds__(384, 5) void offconv_kernel(
    const _Float16* __restrict__ A2th, const _Float16* __restrict__ WTh,
    _Float16* __restrict__ OFFp) {
  const int vb = (blockIdx.x % 216) * 64;
  const int kg = blockIdx.x / 216;          // 0..2
  __shared__ __align__(16) _Float16 Bl[2][64*128];  // 32 KB
  const int t    = threadIdx.x;
  const int lane = t & 63, w = t >> 6;      // w 0..5 = m-tile
  const int l16  = lane & 15, quad = lane >> 4;
  f32x4 acc[4];
  #pragma unroll
  for (int n = 0; n < 4; ++n) acc[n] = (f32x4){0.f,0.f,0.f,0.f};

  const int k0 = kg*9;
  {  // prologue: stage B(k0) -> Bl[0]
    uint4 c0 = ld_chunk(A2th, vb, t,       k0);
    uint4 c1 = ld_chunk(A2th, vb, t + 384, k0);
    uint4 c2 = {0u,0u,0u,0u};
    if (t < 256) c2 = ld_chunk(A2th, vb, t + 768, k0);
    st_chunk(Bl[0], t,       c0);
    st_chunk(Bl[0], t + 384, c1);
    if (t < 256) st_chunk(Bl[0], t + 768, c2);
  }
  __syncthreads();

  for (int i = 0; i < 9; ++i) {
    const int k = k0 + i, bi = i & 1;
    // A-fragments for tap k, direct from global (wave's own m-tile)
    f16x8 af[4];
    #pragma unroll
    for (int ks = 0; ks < 4; ++ks)
      af[ks] = *(const f16x8*)&WTh[(k*96 + (w << 4) + l16)*128 + (ks << 5) + (quad << 3)];
    // issue next tap's B loads
    uint4 c0, c1, c2;
    if (i < 8) {
      c0 = ld_chunk(A2th, vb, t,       k + 1);
      c1 = ld_chunk(A2th, vb, t + 384, k + 1);
      if (t < 256) c2 = ld_chunk(A2th, vb, t + 768, k + 1);
    }
    // MFMA(k)
    #pragma unroll
    for (int ks = 0; ks < 4; ++ks) {
      int gx = (((ks << 2) + quad) ^ l16) << 3;
      #pragma unroll
      for (int n = 0; n < 4; ++n) {
        f16x8 bf = *(const f16x8*)&Bl[bi][((n << 4) + l16)*128 + gx];
        acc[n] = __builtin_amdgcn_mfma_f32_16x16x32_f16(af[ks], bf, acc[n], 0, 0, 0);
      }
    }
    if (i < 8) {
      st_chunk(Bl[bi ^ 1], t,       c0);
      st_chunk(Bl[bi ^ 1], t + 384, c1);
      if (t < 256) st_chunk(Bl[bi ^ 1], t + 768, c2);
      __syncthreads();
    }
  }
  #pragma unroll
  for (int n = 0; n < 4; ++n)
    #pragma unroll
    for (int r = 0; r < 4; ++r) {
      int o = (w << 4) + (quad << 2) + r;
      if (o < 81)
        OFFp[(kg*81 + o)*VS + vb + (n << 4) + l16] = (_Float16)acc[n][r];
    }
}

// ---------------------------------------------------------------------------
// K5: deformable conv, f16 MFMA, single-barrier pipeline.
// iter i (k=k0+i, b=i&1): [af(k) issue][gather(k+1)->Bl[b^1] via M[b^1]]
// [MFMA(k) from Bl[b]][meta(k+2)->M[b]] barrier.  10 barriers total.
// LDS 40 KB -> 4 blocks/CU.
// ---------------------------------------------------------------------------
__global__ __launch_bounds__(256, 3) void deform_kernel(
    const _Float16* __restrict__ A2th, const _Float16* __restrict__ OFFp,
    const float* __restrict__ b_off, const _Float16* __restrict__ WDh,
    _Float16* __restrict__ D0, _Float16* __restrict__ D1,
    _Float16* __restrict__ D2) {
  const int vb = (blockIdx.x % 216) * 64;
  const int kg = blockIdx.x / 216;          // 0..2
  _Float16* DP = (kg == 0) ? D0 : (kg == 1) ? D1 : D2;
  __shared__ __align__(16) _Float16 Bl[2][64*128];  // 32 KB
  __shared__ uint2 M[2][64][8];                     // 8 KB
  const int t    = threadIdx.x;
  const int lane = t & 63, w = t >> 6;
  const int l16  = lane & 15, quad = lane >> 4;
  const int cq = t & 15, vi0 = t >> 4;
  const int mvl = t >> 2, mcp = t & 3;
  const int mv = vb + mvl;
  const int mz = mv / HW, my = (mv / DS) % DS, mx = mv % DS;

  f32x4 acc[2][4];
  #pragma unroll
  for (int i = 0; i < 2; ++i)
    #pragma unroll
    for (int n = 0; n < 4; ++n) acc[i][n] = (f32x4){0.f,0.f,0.f,0.f};

  const int k0 = kg*9;
  {  // meta(k0) -> M[0]
    float p0 = off_sum(OFFp, b_off, k0, 0, mv);
    float p1 = off_sum(OFFp, b_off, k0, 1, mv);
    float p2 = off_sum(OFFp, b_off, k0, 2, mv);
    meta2(k0, mz, my, mx, p0, p1, p2, mcp, &M[0][mvl][0]);
  }
  __syncthreads();
  {  // gather(k0) -> Bl[0]; meta(k0+1) -> M[1]
    gather_tap(A2th, M[0], Bl[0], cq, vi0);
    float p0 = off_sum(OFFp, b_off, k0+1, 0, mv);
    float p1 = off_sum(OFFp, b_off, k0+1, 1, mv);
    float p2 = off_sum(OFFp, b_off, k0+1, 2, mv);
    meta2(k0+1, mz, my, mx, p0, p1, p2, mcp, &M[1][mvl][0]);
  }
  __syncthreads();

  for (int i = 0; i < 9; ++i) {
    const int k = k0 + i, bi = i & 1;
    // A-fragments for tap k (issued first; gather waits cover them)
    f16x8 af0[4], af1[4];
    #pragma unroll
    for (int ks = 0; ks < 4; ++ks) {
      af0[ks] = *(const f16x8*)&WDh[(k*CH + (w<<5) + l16)*CH + (ks<<5) + (quad<<3)];
      af1[ks] = *(const f16x8*)&WDh[(k*CH + (w<<5) + 16 + l16)*CH + (ks<<5) + (quad<<3)];
    }
    // gather(k+1) -> Bl[bi^1] via M[bi^1]
    if (i < 8) gather_tap(A2th, M[bi ^ 1], Bl[bi ^ 1], cq, vi0);
    // MFMA(k) from Bl[bi]
    #pragma unroll
    for (int ks = 0; ks < 4; ++ks) {
      int gx = (((ks << 2) + quad) ^ l16) << 3;
      #pragma unroll
      for (int n = 0; n < 4; ++n) {
        f16x8 bf = *(const f16x8*)&Bl[bi][((n << 4) + l16)*128 + gx];
        acc[0][n] = __builtin_amdgcn_mfma_f32_16x16x32_f16(af0[ks], bf, acc[0][n], 0, 0, 0);
        acc[1][n] = __builtin_amdgcn_mfma_f32_16x16x32_f16(af1[ks], bf, acc[1][n], 0, 0, 0);
      }
    }
    // meta(k+2) -> M[bi]
    if (i < 7) {
      float p0 = off_sum(OFFp, b_off, k+2, 0, mv);
      float p1 = off_sum(OFFp, b_off, k+2, 1, mv);
      float p2 = off_sum(OFFp, b_off, k+2, 2, mv);
      meta2(k+2, mz, my, mx, p0, p1, p2, mcp, &M[bi][mvl][0]);
    }
    if (i < 8) __syncthreads();
  }
  #pragma unroll
  for (int i = 0; i < 2; ++i)
    #pragma unroll
    for (int n = 0; n < 4; ++n)
      #pragma unroll
      for (int r = 0; r < 4; ++r) {
        int o = (w << 5) + (i << 4) + (quad << 2) + r;
        int v = vb + (n << 4) + l16;
        DP[o*VS + v] = (_Float16)acc[i][n][r];
      }
}

// ---------------------------------------------------------------------------
// K6: f16 MFMA 1x1x1 conv + x-multiply, 32-v tiles -> grid 432.
// LDS 40 KB (Wl 32 + Bl 8).
// ---------------------------------------------------------------------------
__global__ __launch_bounds__(256) void pw_mul_kernel(
    const _Float16* __restrict__ D0, const _Float16* __restrict__ D1,
    const _Float16* __restrict__ D2, const float* __restrict__ b_def,
    const _Float16* __restrict__ W1h, const float* __restrict__ b1,
    const float* __restrict__ x, float* __restrict__ out) {
  const int vb = blockIdx.x * 32;
  __shared__ __align__(16) _Float16 Wl[128*128]; // 32 KB
  __shared__ __align__(16) _Float16 Bl[32*128];  // 8 KB
  const int t    = threadIdx.x;
  const int lane = t & 63, w = t >> 6;
  const int l16  = lane & 15, quad = lane >> 4;
  const int wo = t >> 4, wcg = t & 15;
  #pragma unroll
  for (int i = 0; i < 8; ++i) {
    int o = wo + 16*i;
    *(uint4*)&Wl[o*128 + ((wcg ^ (o & 15)) << 3)] =
        *(const uint4*)&W1h[o*128 + (wcg << 3)];
  }
  {
    const int vsq = t & 7;     // v = 4*vsq..4*vsq+3
    const int c0  = t >> 3;    // c = c0 + 32*i
    #pragma unroll
    for (int i = 0; i < 4; ++i) {
      int c = c0 + (i << 5);
      float bd = b_def[c];
      int base = c*VS + vb + (vsq << 2);
      h4 a0 = *(const h4*)&D0[base];
      h4 a1 = *(const h4*)&D1[base];
      h4 a2 = *(const h4*)&D2[base];
      #pragma unroll
      for (int j = 0; j < 4; ++j) {
        float sum = (float)a0[j] + (float)a1[j] + (float)a2[j] + bd;
        int row = (vsq << 2) + j;
        Bl[row*128 + (((c >> 3) ^ (row & 15)) << 3) + (c & 7)] = (_Float16)sum;
      }
    }
  }
  __syncthreads();
  f32x4 acc[2][2];
  #pragma unroll
  for (int i = 0; i < 2; ++i)
    #pragma unroll
    for (int n = 0; n < 2; ++n) acc[i][n] = (f32x4){0.f,0.f,0.f,0.f};
  #pragma unroll
  for (int ks = 0; ks < 4; ++ks) {
    int gx = (((ks << 2) + quad) ^ l16) << 3;
    f16x8 a0 = *(const f16x8*)&Wl[((w << 5) + l16)*128 + gx];
    f16x8 a1 = *(const f16x8*)&Wl[((w << 5) + 16 + l16)*128 + gx];
    #pragma unroll
    for (int n = 0; n < 2; ++n) {
      f16x8 bf = *(const f16x8*)&Bl[((n << 4) + l16)*128 + gx];
      acc[0][n] = __builtin_amdgcn_mfma_f32_16x16x32_f16(a0, bf, acc[0][n], 0, 0, 0);
      acc[1][n] = __builtin_amdgcn_mfma_f32_16x16x32_f16(a1, bf, acc[1][n], 0, 0, 0);
    }
  }
  #pragma unroll
  for (int i = 0; i < 2; ++i)
    #pragma unroll
    for (int n = 0; n < 2; ++n)
      #pragma unroll
      for (int r = 0; r < 4; ++r) {
        int o = (w << 5) + (i << 4) + (quad << 2) + r;
        int v = vb + (n << 4) + l16;
        out[o*VS + v] = x[o*VS + v] * (acc[i][n][r] + b1[o]);
      }
}

// ---------------------------------------------------------------------------
// Workspace (floats, total 5,613,824 f = 22.5 MB):
//   [0        , 1769472)  A1 fp32 (dw5 out) -> later D0,D1 fp16
//   [1769472  , 2654208)  A2th [V][128] fp16
//   [2654208  , 4333824)  OFFp [3][81][V] fp16
//   [4333824  , 5218560)  D2 fp16
//   [5218560  , ...)      WTh fp16 | WDh fp16 | W1h fp16
// ---------------------------------------------------------------------------
extern "C" void kernel_launch(void* const* d_in, const int* in_sizes, int n_in,
                              void* d_out, int out_size, void* d_ws, size_t ws_size,
                              hipStream_t stream) {
  (void)in_sizes; (void)n_in; (void)out_size; (void)ws_size;
  const float* x     = (const float*)d_in[0];
  const float* w0    = (const float*)d_in[1];
  const float* b0    = (const float*)d_in[2];
  const float* wsw   = (const float*)d_in[3];
  const float* bs    = (const float*)d_in[4];
  const float* w_off = (const float*)d_in[5];
  const float* b_off = (const float*)d_in[6];
  const float* w_def = (const float*)d_in[7];
  const float* b_def = (const float*)d_in[8];
  const float* w1    = (const float*)d_in[9];
  const float* b1    = (const float*)d_in[10];
  float* out = (float*)d_out;

  float* wsf = (float*)d_ws;
  float*     A1   = wsf;
  _Float16*  A2th = (_Float16*)(wsf + 1769472);
  _Float16*  OFFp = (_Float16*)(wsf + 2654208);
  _Float16*  D2   = (_Float16*)(wsf + 4333824);
  _Float16*  WTh  = (_Float16*)(wsf + 5218560);
  _Float16*  WDh  = WTh + 331776;
  _Float16*  W1h  = WDh + 442368;
  _Float16*  D0   = (_Float16*)A1;          // A1 dead after dwdil
  _Float16*  D1   = D0 + 128*VS;

  prep_weights  <<<225,  256, 0, stream>>>(w_off, w_def, w1, WTh, WDh, W1h);
  dw5_kernel    <<<1024, 256, 0, stream>>>(x, w0, b0, A1);
  dwdil_kernel  <<<768,  256, 0, stream>>>(A1, wsw, bs, A2th);
  offconv_kernel<<<648,  384, 0, stream>>>(A2th, WTh, OFFp);
  deform_kernel <<<648,  256, 0, stream>>>(A2th, OFFp, b_off, WDh, D0, D1, D2);
  pw_mul_kernel <<<432,  256, 0, stream>>>(D0, D1, D2, b_def, W1h, b1, x, out);
}

// Round 9
// 220.271 us; speedup vs baseline: 1.8546x; 1.3464x over previous
//
#include <hip/hip_runtime.h>

#define CH 128
#define DS 24
#define HW (DS*DS)      // 576
#define VS (DS*DS*DS)   // 13824

typedef _Float16 f16x8 __attribute__((ext_vector_type(8)));
typedef _Float16 half2v __attribute__((ext_vector_type(2)));
typedef __attribute__((ext_vector_type(4))) float f32x4;
typedef _Float16 h4 __attribute__((ext_vector_type(4)));

__device__ __forceinline__ half2v u2h(unsigned u) {
  union { unsigned u; half2v h; } v; v.u = u; return v.h;
}
__device__ __forceinline__ unsigned h2u(half2v h) {
  union { unsigned u; half2v h; } v; v.h = h; return v.u;
}

// sum of 3 fp16 offset partials + bias, row = 3*kn+a
__device__ __forceinline__ float off_sum(const _Float16* __restrict__ OFFp,
                                         const float* __restrict__ b_off,
                                         int kn, int a, int mv) {
  int row = 3*kn + a;
  return (float)OFFp[row*VS + mv] + (float)OFFp[(81 + row)*VS + mv]
       + (float)OFFp[(162 + row)*VS + mv] + b_off[row];
}

// this thread's 2 trilinear corners for tap kn -> Mrow[corner]
__device__ __forceinline__ void meta2(int kn, int mz, int my, int mx,
                                      float po0, float po1, float po2,
                                      int mcp, uint2* Mrow) {
  float cz = (float)(mz + kn/9     - 1) + po0;
  float cy = (float)(my + (kn/3)%3 - 1) + po1;
  float cx = (float)(mx + kn%3     - 1) + po2;
  float fz = floorf(cz), fy = floorf(cy), fx = floorf(cx);
  int iz = (int)fz, iy = (int)fy, ix = (int)fx;
  float rz = cz - fz, ry = cy - fy, rx = cx - fx;
  #pragma unroll
  for (int c2 = 0; c2 < 2; ++c2) {
    int corner = mcp*2 + c2;
    int ca = corner >> 2, cb = (corner >> 1) & 1, cc = corner & 1;
    int zi = iz + ca, yi = iy + cb, xi = ix + cc;
    float ww = (ca ? rz : 1.f-rz) * (cb ? ry : 1.f-ry) * (cc ? rx : 1.f-rx);
    bool valid = ((unsigned)zi < 24u) && ((unsigned)yi < 24u) && ((unsigned)xi < 24u);
    float wv = valid ? ww : 0.f;
    half2v wp = {(_Float16)wv, (_Float16)wv};
    int idx = valid ? (zi*DS + yi)*DS + xi : 0;
    Mrow[corner] = make_uint2(h2u(wp), (unsigned)(idx << 7));
  }
}

// gather one tap's 64x128 B-tile into BlBuf using meta Mb
__device__ __forceinline__ void gather_tap(
    const _Float16* __restrict__ A2th, const uint2 (*Mb)[8],
    _Float16* BlBuf, int cq, int vi0) {
  #pragma unroll
  for (int p = 0; p < 4; ++p) {
    int vl = (p << 4) + vi0;
    half2v a0 = {(_Float16)0.f, (_Float16)0.f};
    half2v a1 = a0, a2 = a0, a3 = a0;
    #pragma unroll
    for (int corner = 0; corner < 8; ++corner) {
      uint2 m = Mb[vl][corner];
      half2v wp = u2h(m.x);
      uint4 g = *(const uint4*)&A2th[m.y + (cq << 3)];
      a0 += u2h(g.x) * wp;
      a1 += u2h(g.y) * wp;
      a2 += u2h(g.z) * wp;
      a3 += u2h(g.w) * wp;
    }
    uint4 pk = {h2u(a0), h2u(a1), h2u(a2), h2u(a3)};
    *(uint4*)&BlBuf[vl*128 + ((cq ^ (vl & 15)) << 3)] = pk;
  }
}

// offconv B chunk: masked shifted-row load / swizzled store
__device__ __forceinline__ uint4 ld_chunk(const _Float16* __restrict__ A2th,
                                          int vb, int s, int k) {
  int vl = s >> 4, cq = s & 15;
  int v = vb + vl;
  int z = v / HW, y = (v / DS) % DS, xx = v % DS;
  int dz = k/9 - 1, dy = (k/3)%3 - 1, dx = k%3 - 1;
  uint4 pk = {0u,0u,0u,0u};
  int zz = z + dz, yy = y + dy, xq = xx + dx;
  if ((unsigned)zz < 24u && (unsigned)yy < 24u && (unsigned)xq < 24u)
    pk = *(const uint4*)&A2th[(v + (dz*DS + dy)*DS + dx)*CH + (cq << 3)];
  return pk;
}
__device__ __forceinline__ void st_chunk(_Float16* Bb, int s, uint4 pk) {
  int vl = s >> 4, cq = s & 15;
  *(uint4*)&Bb[vl*128 + ((cq ^ (vl & 15)) << 3)] = pk;
}

// ---------------------------------------------------------------------------
// K0: weight prep, coalesced via LDS transpose.
// ---------------------------------------------------------------------------
__global__ __launch_bounds__(256) void prep_weights(
    const float* __restrict__ w_off, const float* __restrict__ w_def,
    const float* __restrict__ w1,
    _Float16* __restrict__ WTh, _Float16* __restrict__ WDh,
    _Float16* __restrict__ W1h) {
  __shared__ float sbuf[3456];
  const int b = blockIdx.x, t = threadIdx.x;
  if (b < 96) {
    const int o = b;
    if (o < 81) {
      for (int s = t; s < 3456; s += 256) sbuf[s] = w_off[o*3456 + s];
      __syncthreads();
      for (int s = t; s < 3456; s += 256) {
        int k = s >> 7, c = s & 127;
        WTh[(k*96 + o)*128 + c] = (_Float16)sbuf[c*27 + k];
      }
    } else {
      for (int s = t; s < 3456; s += 256) {
        int k = s >> 7, c = s & 127;
        WTh[(k*96 + o)*128 + c] = (_Float16)0.f;
      }
    }
  } else if (b < 224) {
    const int o = b - 96;
    for (int s = t; s < 3456; s += 256) sbuf[s] = w_def[o*3456 + s];
    __syncthreads();
    for (int s = t; s < 3456; s += 256) {
      int k = s >> 7, c = s & 127;
      WDh[(k*128 + o)*128 + c] = (_Float16)sbuf[c*27 + k];
    }
  } else {
    for (int s = t; s < 16384; s += 256) W1h[s] = (_Float16)w1[s];
  }
}

// ---------------------------------------------------------------------------
// K1: depthwise 5x5x5, pad=2 — LDS-FREE row-register version.
// thread <-> (z,y); whole 24-wide x-row accumulated in registers; per
// (kz,ky) tap-row: 6 aligned float4 global loads (L1/L2-cached, 25x row
// reuse across lanes/taps) -> 120 FMA.  Only LDS: 125-float weight
// broadcast (conflict-free).  grid = 128 ch x 3 z-slabs, 192 thr.
// ---------------------------------------------------------------------------
__global__ __launch_bounds__(192) void dw5_kernel(
    const float* __restrict__ x, const float* __restrict__ w0,
    const float* __restrict__ b0, float* __restrict__ A1) {
  const int c  = blockIdx.x / 3;
  const int zb = (blockIdx.x % 3) * 8;
  __shared__ float sw[125];
  const int t = threadIdx.x;
  if (t < 125) sw[t] = w0[c*125 + t];
  __syncthreads();
  const int z = zb + t / 24, y = t % 24;
  const float* xc = x + c*VS;
  float acc[24];
  #pragma unroll
  for (int o = 0; o < 24; ++o) acc[o] = 0.f;
  #pragma unroll
  for (int kz = 0; kz < 5; ++kz) {
    int zz = z + kz - 2;
    if ((unsigned)zz >= 24u) continue;
    #pragma unroll
    for (int ky = 0; ky < 5; ++ky) {
      int yy = y + ky - 2;
      if ((unsigned)yy >= 24u) continue;
      const float* row = &xc[(zz*DS + yy)*DS];
      float f[24];
      #pragma unroll
      for (int q = 0; q < 6; ++q) {
        float4 r = *(const float4*)(row + 4*q);
        f[4*q] = r.x; f[4*q+1] = r.y; f[4*q+2] = r.z; f[4*q+3] = r.w;
      }
      const float* wr = &sw[(kz*5 + ky)*5];
      #pragma unroll
      for (int kx = 0; kx < 5; ++kx) {
        float w = wr[kx];
        #pragma unroll
        for (int o = 0; o < 24; ++o) {
          int xi = o + kx - 2;                 // static per unrolled instance
          if (xi >= 0 && xi < 24) acc[o] = fmaf(w, f[xi], acc[o]);
        }
      }
    }
  }
  const float bias = b0[c];
  float* orow = &A1[c*VS + (z*DS + y)*DS];
  #pragma unroll
  for (int q = 0; q < 6; ++q)
    *(float4*)(orow + 4*q) = make_float4(acc[4*q]+bias, acc[4*q+1]+bias,
                                         acc[4*q+2]+bias, acc[4*q+3]+bias);
}

// ---------------------------------------------------------------------------
// K2: depthwise 5x5x5 dil=3 pad=6 — LDS-FREE row-register version, fused
// fp16 transpose store to A2th[v][128 c].  Same structure as K1 with
// dilation-3 static tap indices.
// ---------------------------------------------------------------------------
__global__ __launch_bounds__(192) void dwdil_kernel(
    const float* __restrict__ A1, const float* __restrict__ wgt,
    const float* __restrict__ bs, _Float16* __restrict__ A2th) {
  const int c  = blockIdx.x / 3;
  const int zb = (blockIdx.x % 3) * 8;
  __shared__ float sw[125];
  const int t = threadIdx.x;
  if (t < 125) sw[t] = wgt[c*125 + t];
  __syncthreads();
  const int z = zb + t / 24, y = t % 24;
  const float* xc = A1 + c*VS;
  float acc[24];
  #pragma unroll
  for (int o = 0; o < 24; ++o) acc[o] = 0.f;
  #pragma unroll
  for (int kz = 0; kz < 5; ++kz) {
    int zz = z + 3*kz - 6;
    if ((unsigned)zz >= 24u) continue;
    #pragma unroll
    for (int ky = 0; ky < 5; ++ky) {
      int yy = y + 3*ky - 6;
      if ((unsigned)yy >= 24u) continue;
      const float* row = &xc[(zz*DS + yy)*DS];
      float f[24];
      #pragma unroll
      for (int q = 0; q < 6; ++q) {
        float4 r = *(const float4*)(row + 4*q);
        f[4*q] = r.x; f[4*q+1] = r.y; f[4*q+2] = r.z; f[4*q+3] = r.w;
      }
      const float* wr = &sw[(kz*5 + ky)*5];
      #pragma unroll
      for (int kx = 0; kx < 5; ++kx) {
        float w = wr[kx];
        #pragma unroll
        for (int o = 0; o < 24; ++o) {
          int xi = o + 3*kx - 6;               // static per unrolled instance
          if (xi >= 0 && xi < 24) acc[o] = fmaf(w, f[xi], acc[o]);
        }
      }
    }
  }
  const float bias = bs[c];
  _Float16* dst = &A2th[(z*DS + y)*DS*CH + c];
  #pragma unroll
  for (int o = 0; o < 24; ++o)
    dst[o*CH] = (_Float16)(acc[o] + bias);
}

// ---------------------------------------------------------------------------
// K4: offset conv, f16 MFMA, 384-thread/6-wave blocks (wave = m-tile, A-frags
// direct from global -> no Wl).  Double-buffered Bl, single barrier per tap.
// ---------------------------------------------------------------------------
__global__ __launch_bounds__(384, 5) void offconv_kernel(
    const _Float16* __restrict__ A2th, const _Float16* __restrict__ WTh,
    _Float16* __restrict__ OFFp) {
  const int vb = (blockIdx.x % 216) * 64;
  const int kg = blockIdx.x / 216;          // 0..2
  __shared__ __align__(16) _Float16 Bl[2][64*128];  // 32 KB
  const int t    = threadIdx.x;
  const int lane = t & 63, w = t >> 6;      // w 0..5 = m-tile
  const int l16  = lane & 15, quad = lane >> 4;
  f32x4 acc[4];
  #pragma unroll
  for (int n = 0; n < 4; ++n) acc[n] = (f32x4){0.f,0.f,0.f,0.f};

  const int k0 = kg*9;
  {  // prologue: stage B(k0) -> Bl[0]
    uint4 c0 = ld_chunk(A2th, vb, t,       k0);
    uint4 c1 = ld_chunk(A2th, vb, t + 384, k0);
    uint4 c2 = {0u,0u,0u,0u};
    if (t < 256) c2 = ld_chunk(A2th, vb, t + 768, k0);
    st_chunk(Bl[0], t,       c0);
    st_chunk(Bl[0], t + 384, c1);
    if (t < 256) st_chunk(Bl[0], t + 768, c2);
  }
  __syncthreads();

  for (int i = 0; i < 9; ++i) {
    const int k = k0 + i, bi = i & 1;
    f16x8 af[4];
    #pragma unroll
    for (int ks = 0; ks < 4; ++ks)
      af[ks] = *(const f16x8*)&WTh[(k*96 + (w << 4) + l16)*128 + (ks << 5) + (quad << 3)];
    uint4 c0, c1, c2;
    if (i < 8) {
      c0 = ld_chunk(A2th, vb, t,       k + 1);
      c1 = ld_chunk(A2th, vb, t + 384, k + 1);
      if (t < 256) c2 = ld_chunk(A2th, vb, t + 768, k + 1);
    }
    #pragma unroll
    for (int ks = 0; ks < 4; ++ks) {
      int gx = (((ks << 2) + quad) ^ l16) << 3;
      #pragma unroll
      for (int n = 0; n < 4; ++n) {
        f16x8 bf = *(const f16x8*)&Bl[bi][((n << 4) + l16)*128 + gx];
        acc[n] = __builtin_amdgcn_mfma_f32_16x16x32_f16(af[ks], bf, acc[n], 0, 0, 0);
      }
    }
    if (i < 8) {
      st_chunk(Bl[bi ^ 1], t,       c0);
      st_chunk(Bl[bi ^ 1], t + 384, c1);
      if (t < 256) st_chunk(Bl[bi ^ 1], t + 768, c2);
      __syncthreads();
    }
  }
  #pragma unroll
  for (int n = 0; n < 4; ++n)
    #pragma unroll
    for (int r = 0; r < 4; ++r) {
      int o = (w << 4) + (quad << 2) + r;
      if (o < 81)
        OFFp[(kg*81 + o)*VS + vb + (n << 4) + l16] = (_Float16)acc[n][r];
    }
}

// ---------------------------------------------------------------------------
// K5: deformable conv, f16 MFMA, single-barrier pipeline.
// ---------------------------------------------------------------------------
__global__ __launch_bounds__(256, 3) void deform_kernel(
    const _Float16* __restrict__ A2th, const _Float16* __restrict__ OFFp,
    const float* __restrict__ b_off, const _Float16* __restrict__ WDh,
    _Float16* __restrict__ D0, _Float16* __restrict__ D1,
    _Float16* __restrict__ D2) {
  const int vb = (blockIdx.x % 216) * 64;
  const int kg = blockIdx.x / 216;          // 0..2
  _Float16* DP = (kg == 0) ? D0 : (kg == 1) ? D1 : D2;
  __shared__ __align__(16) _Float16 Bl[2][64*128];  // 32 KB
  __shared__ uint2 M[2][64][8];                     // 8 KB
  const int t    = threadIdx.x;
  const int lane = t & 63, w = t >> 6;
  const int l16  = lane & 15, quad = lane >> 4;
  const int cq = t & 15, vi0 = t >> 4;
  const int mvl = t >> 2, mcp = t & 3;
  const int mv = vb + mvl;
  const int mz = mv / HW, my = (mv / DS) % DS, mx = mv % DS;

  f32x4 acc[2][4];
  #pragma unroll
  for (int i = 0; i < 2; ++i)
    #pragma unroll
    for (int n = 0; n < 4; ++n) acc[i][n] = (f32x4){0.f,0.f,0.f,0.f};

  const int k0 = kg*9;
  {
    float p0 = off_sum(OFFp, b_off, k0, 0, mv);
    float p1 = off_sum(OFFp, b_off, k0, 1, mv);
    float p2 = off_sum(OFFp, b_off, k0, 2, mv);
    meta2(k0, mz, my, mx, p0, p1, p2, mcp, &M[0][mvl][0]);
  }
  __syncthreads();
  {
    gather_tap(A2th, M[0], Bl[0], cq, vi0);
    float p0 = off_sum(OFFp, b_off, k0+1, 0, mv);
    float p1 = off_sum(OFFp, b_off, k0+1, 1, mv);
    float p2 = off_sum(OFFp, b_off, k0+1, 2, mv);
    meta2(k0+1, mz, my, mx, p0, p1, p2, mcp, &M[1][mvl][0]);
  }
  __syncthreads();

  for (int i = 0; i < 9; ++i) {
    const int k = k0 + i, bi = i & 1;
    f16x8 af0[4], af1[4];
    #pragma unroll
    for (int ks = 0; ks < 4; ++ks) {
      af0[ks] = *(const f16x8*)&WDh[(k*CH + (w<<5) + l16)*CH + (ks<<5) + (quad<<3)];
      af1[ks] = *(const f16x8*)&WDh[(k*CH + (w<<5) + 16 + l16)*CH + (ks<<5) + (quad<<3)];
    }
    if (i < 8) gather_tap(A2th, M[bi ^ 1], Bl[bi ^ 1], cq, vi0);
    #pragma unroll
    for (int ks = 0; ks < 4; ++ks) {
      int gx = (((ks << 2) + quad) ^ l16) << 3;
      #pragma unroll
      for (int n = 0; n < 4; ++n) {
        f16x8 bf = *(const f16x8*)&Bl[bi][((n << 4) + l16)*128 + gx];
        acc[0][n] = __builtin_amdgcn_mfma_f32_16x16x32_f16(af0[ks], bf, acc[0][n], 0, 0, 0);
        acc[1][n] = __builtin_amdgcn_mfma_f32_16x16x32_f16(af1[ks], bf, acc[1][n], 0, 0, 0);
      }
    }
    if (i < 7) {
      float p0 = off_sum(OFFp, b_off, k+2, 0, mv);
      float p1 = off_sum(OFFp, b_off, k+2, 1, mv);
      float p2 = off_sum(OFFp, b_off, k+2, 2, mv);
      meta2(k+2, mz, my, mx, p0, p1, p2, mcp, &M[bi][mvl][0]);
    }
    if (i < 8) __syncthreads();
  }
  #pragma unroll
  for (int i = 0; i < 2; ++i)
    #pragma unroll
    for (int n = 0; n < 4; ++n)
      #pragma unroll
      for (int r = 0; r < 4; ++r) {
        int o = (w << 5) + (i << 4) + (quad << 2) + r;
        int v = vb + (n << 4) + l16;
        DP[o*VS + v] = (_Float16)acc[i][n][r];
      }
}

// ---------------------------------------------------------------------------
// K6: f16 MFMA 1x1x1 conv + x-multiply, 32-v tiles -> grid 432.
// ---------------------------------------------------------------------------
__global__ __launch_bounds__(256) void pw_mul_kernel(
    const _Float16* __restrict__ D0, const _Float16* __restrict__ D1,
    const _Float16* __restrict__ D2, const float* __restrict__ b_def,
    const _Float16* __restrict__ W1h, const float* __restrict__ b1,
    const float* __restrict__ x, float* __restrict__ out) {
  const int vb = blockIdx.x * 32;
  __shared__ __align__(16) _Float16 Wl[128*128]; // 32 KB
  __shared__ __align__(16) _Float16 Bl[32*128];  // 8 KB
  const int t    = threadIdx.x;
  const int lane = t & 63, w = t >> 6;
  const int l16  = lane & 15, quad = lane >> 4;
  const int wo = t >> 4, wcg = t & 15;
  #pragma unroll
  for (int i = 0; i < 8; ++i) {
    int o = wo + 16*i;
    *(uint4*)&Wl[o*128 + ((wcg ^ (o & 15)) << 3)] =
        *(const uint4*)&W1h[o*128 + (wcg << 3)];
  }
  {
    const int vsq = t & 7;     // v = 4*vsq..4*vsq+3
    const int c0  = t >> 3;    // c = c0 + 32*i
    #pragma unroll
    for (int i = 0; i < 4; ++i) {
      int c = c0 + (i << 5);
      float bd = b_def[c];
      int base = c*VS + vb + (vsq << 2);
      h4 a0 = *(const h4*)&D0[base];
      h4 a1 = *(const h4*)&D1[base];
      h4 a2 = *(const h4*)&D2[base];
      #pragma unroll
      for (int j = 0; j < 4; ++j) {
        float sum = (float)a0[j] + (float)a1[j] + (float)a2[j] + bd;
        int row = (vsq << 2) + j;
        Bl[row*128 + (((c >> 3) ^ (row & 15)) << 3) + (c & 7)] = (_Float16)sum;
      }
    }
  }
  __syncthreads();
  f32x4 acc[2][2];
  #pragma unroll
  for (int i = 0; i < 2; ++i)
    #pragma unroll
    for (int n = 0; n < 2; ++n) acc[i][n] = (f32x4){0.f,0.f,0.f,0.f};
  #pragma unroll
  for (int ks = 0; ks < 4; ++ks) {
    int gx = (((ks << 2) + quad) ^ l16) << 3;
    f16x8 a0 = *(const f16x8*)&Wl[((w << 5) + l16)*128 + gx];
    f16x8 a1 = *(const f16x8*)&Wl[((w << 5) + 16 + l16)*128 + gx];
    #pragma unroll
    for (int n = 0; n < 2; ++n) {
      f16x8 bf = *(const f16x8*)&Bl[((n << 4) + l16)*128 + gx];
      acc[0][n] = __builtin_amdgcn_mfma_f32_16x16x32_f16(a0, bf, acc[0][n], 0, 0, 0);
      acc[1][n] = __builtin_amdgcn_mfma_f32_16x16x32_f16(a1, bf, acc[1][n], 0, 0, 0);
    }
  }
  #pragma unroll
  for (int i = 0; i < 2; ++i)
    #pragma unroll
    for (int n = 0; n < 2; ++n)
      #pragma unroll
      for (int r = 0; r < 4; ++r) {
        int o = (w << 5) + (i << 4) + (quad << 2) + r;
        int v = vb + (n << 4) + l16;
        out[o*VS + v] = x[o*VS + v] * (acc[i][n][r] + b1[o]);
      }
}

// ---------------------------------------------------------------------------
// Workspace (floats, total 5,613,824 f = 22.5 MB):
//   [0        , 1769472)  A1 fp32 (dw5 out) -> later D0,D1 fp16
//   [1769472  , 2654208)  A2th [V][128] fp16
//   [2654208  , 4333824)  OFFp [3][81][V] fp16
//   [4333824  , 5218560)  D2 fp16
//   [5218560  , ...)      WTh fp16 | WDh fp16 | W1h fp16
// ---------------------------------------------------------------------------
extern "C" void kernel_launch(void* const* d_in, const int* in_sizes, int n_in,
                              void* d_out, int out_size, void* d_ws, size_t ws_size,
                              hipStream_t stream) {
  (void)in_sizes; (void)n_in; (void)out_size; (void)ws_size;
  const float* x     = (const float*)d_in[0];
  const float* w0    = (const float*)d_in[1];
  const float* b0    = (const float*)d_in[2];
  const float* wsw   = (const float*)d_in[3];
  const float* bs    = (const float*)d_in[4];
  const float* w_off = (const float*)d_in[5];
  const float* b_off = (const float*)d_in[6];
  const float* w_def = (const float*)d_in[7];
  const float* b_def = (const float*)d_in[8];
  const float* w1    = (const float*)d_in[9];
  const float* b1    = (const float*)d_in[10];
  float* out = (float*)d_out;

  float* wsf = (float*)d_ws;
  float*     A1   = wsf;
  _Float16*  A2th = (_Float16*)(wsf + 1769472);
  _Float16*  OFFp = (_Float16*)(wsf + 2654208);
  _Float16*  D2   = (_Float16*)(wsf + 4333824);
  _Float16*  WTh  = (_Float16*)(wsf + 5218560);
  _Float16*  WDh  = WTh + 331776;
  _Float16*  W1h  = WDh + 442368;
  _Float16*  D0   = (_Float16*)A1;          // A1 dead after dwdil
  _Float16*  D1   = D0 + 128*VS;

  prep_weights  <<<225, 256, 0, stream>>>(w_off, w_def, w1, WTh, WDh, W1h);
  dw5_kernel    <<<384, 192, 0, stream>>>(x, w0, b0, A1);
  dwdil_kernel  <<<384, 192, 0, stream>>>(A1, wsw, bs, A2th);
  offconv_kernel<<<648, 384, 0, stream>>>(A2th, WTh, OFFp);
  deform_kernel <<<648, 256, 0, stream>>>(A2th, OFFp, b_off, WDh, D0, D1, D2);
  pw_mul_kernel <<<432, 256, 0, stream>>>(D0, D1, D2, b_def, W1h, b1, x, out);
}